// Round 3
// baseline (217.976 us; speedup 1.0000x reference)
//
#include <hip/hip_runtime.h>
#include <stdint.h>

typedef unsigned short u16;
typedef unsigned int u32;
typedef __bf16 bf16x8 __attribute__((ext_vector_type(8)));
typedef float floatx4 __attribute__((ext_vector_type(4)));

#define DEVI static __device__ __forceinline__

DEVI u16 f2bf(float f) {
  uint32_t u = __builtin_bit_cast(uint32_t, f);
  u += 0x7FFFu + ((u >> 16) & 1u);
  return (u16)(u >> 16);
}
DEVI float bf2f(u16 b) { return __builtin_bit_cast(float, (uint32_t)b << 16); }

// order-preserving float<->uint encoding for atomicMax
DEVI u32 encf(float f) {
  u32 u = __builtin_bit_cast(u32, f);
  return (u >> 31) ? ~u : (u | 0x80000000u);
}
DEVI float decf(u32 e) {
  u32 u = (e >> 31) ? (e & 0x7FFFFFFFu) : ~e;
  return __builtin_bit_cast(float, u);
}

// ---- workspace layout (bytes) ----
static constexpr size_t OFF_SATT  = 0;                       // bf16 [m][cb][y][x][c8] 4.72MB
static constexpr size_t OFF_GRDP  = OFF_SATT + (size_t)8*4*96*96*8*2;   // bf16 [cb][i*32+j][col16][c8] 1.05MB
static constexpr size_t OFF_S2    = OFF_GRDP + (size_t)4*1024*16*8*2;   // f32 [8][96][96]
static constexpr size_t OFF_PART  = OFF_S2   + (size_t)73728*4;         // f32 [8][65][65]
static constexpr size_t OFF_NRM   = OFF_PART + (size_t)33800*4;         // f32 grd_nrm2[8], sat_nrm2[8]
static constexpr size_t OFF_SIM   = OFF_NRM  + 64;                      // u32 enc sim[8][8]
static constexpr size_t OFF_VDIAG = OFF_SIM  + 256;                     // f32 [8][65][65]
static constexpr size_t OFF_MASK  = OFF_VDIAG + (size_t)33800*4;        // f32 [8][1024]

// ---- K1: prep. blocks 0..383: sat -> bf16 channels-last (coalesced via LDS transpose)
//          blocks 384..391: grd -> packed hi|lo cols + norm + channel-sum mask.
__global__ void k_prep(const float* __restrict__ grd, const float* __restrict__ sat,
                       u16* __restrict__ sTh, u16* __restrict__ gP,
                       float* __restrict__ s2, float* __restrict__ nrm,
                       float* __restrict__ gmask) {
  __shared__ float L[2*32*97];        // 24832 B
  __shared__ float red[256];
  const int t = threadIdx.x;
  if (blockIdx.x < 384) {
    const int m  = blockIdx.x / 48;
    const int yp = blockIdx.x - (blockIdx.x / 48) * 48;
    #pragma unroll
    for (int k = 0; k < 6; ++k) {
      const int idx = k*256 + t;
      const int row = idx / 768;
      const int r2  = idx - row*768;
      const int c   = r2 / 24;
      const int xq  = r2 - c*24;
      const int y   = yp*2 + row;
      const float4 v = *(const float4*)(sat + (((size_t)m*32 + c)*128 + (16+y))*128 + 16 + xq*4);
      float* Lp = &L[(row*32 + c)*97 + xq*4];
      Lp[0]=v.x; Lp[1]=v.y; Lp[2]=v.z; Lp[3]=v.w;
    }
    __syncthreads();
    float ss = 0.f;
    if (t < 192) {
      const int row = t / 96, x = t - (t/96)*96;
      #pragma unroll
      for (int c = 0; c < 32; ++c) { const float v = L[(row*32+c)*97 + x]; ss += v*v; }
      s2[(size_t)m*9216 + (yp*2+row)*96 + x] = ss;
    }
    red[t] = ss; __syncthreads();
    for (int s = 128; s > 0; s >>= 1) { if (t < s) red[t] += red[t+s]; __syncthreads(); }
    if (t == 0) atomicAdd(&nrm[8+m], red[0]);
    #pragma unroll
    for (int k = 0; k < 3; ++k) {
      const int o   = k*256 + t;
      const int row = o / 384;
      const int r2  = o - row*384;
      const int cb  = r2 / 96;
      const int x   = r2 - cb*96;
      union { u16 us[8]; uint4 v4; } P;
      #pragma unroll
      for (int e = 0; e < 8; ++e) P.us[e] = f2bf(L[(row*32 + cb*8 + e)*97 + x]);
      *(uint4*)(&sTh[(((size_t)m*4+cb)*9216 + (size_t)(yp*2+row)*96 + x)*8]) = P.v4;
    }
  } else {
    const int n = blockIdx.x - 384;
    float nn = 0.f, scs[4];
    #pragma unroll
    for (int it = 0; it < 4; ++it) {
      const int pidx = it*256 + t;
      float vals[32]; float sc = 0.f;
      #pragma unroll
      for (int c = 0; c < 32; ++c) {
        const float v = grd[((size_t)n*32 + c)*1024 + pidx];
        vals[c] = v; sc += v; nn += v*v;
      }
      scs[it] = sc;
      #pragma unroll
      for (int cb = 0; cb < 4; ++cb) {
        union { u16 us[8]; uint4 v4; } ph, pl;
        #pragma unroll
        for (int e = 0; e < 8; ++e) {
          const float v = vals[cb*8+e];
          const u16 h = f2bf(v); ph.us[e] = h; pl.us[e] = f2bf(v - bf2f(h));
        }
        const size_t o = ((size_t)cb*1024 + pidx)*128;
        *(uint4*)(&gP[o + (size_t)n*8])     = ph.v4;
        *(uint4*)(&gP[o + (size_t)(n+8)*8]) = pl.v4;
      }
    }
    red[t] = nn; __syncthreads();
    for (int s = 128; s > 0; s >>= 1) { if (t < s) red[t] += red[t+s]; __syncthreads(); }
    const float gn = fmaxf(sqrtf(red[0]), 1e-12f);
    if (t == 0) nrm[n] = red[0];
    const float thr = 1e-6f * gn;
    #pragma unroll
    for (int it = 0; it < 4; ++it)
      gmask[n*1024 + it*256 + t] = (fabsf(scs[it]) > thr) ? 1.f : 0.f;
  }
}

// ---- K2: 32x32 window sum of s2; grid 104 = (m, 5-row slab) ----
__global__ void k_win(const float* __restrict__ s2, float* __restrict__ part) {
  __shared__ float hs[36*65];
  const int b = blockIdx.x, t = threadIdx.x;
  const int m = b / 13, yt = b - (b/13)*13;
  const int ybase = yt * 5;
  const float* sp = s2 + (size_t)m*9216;
  for (int idx = t; idx < 36*65; idx += 256) {
    const int rho = idx / 65, xo = idx - rho*65;
    const float* r = sp + (ybase + rho)*96 + xo;
    float s = 0.f;
    #pragma unroll
    for (int j = 0; j < 32; ++j) s += r[j];
    hs[idx] = s;
  }
  __syncthreads();
  for (int idx = t; idx < 5*65; idx += 256) {
    const int yo = idx / 65, xo = idx - yo*65;
    float s = 0.f;
    #pragma unroll
    for (int i = 0; i < 32; ++i) s += hs[(yo+i)*65 + xo];
    part[(size_t)m*4225 + (size_t)(ybase+yo)*65 + xo] = s;
  }
}

// ---- K3: conv with fused normalize/max epilogue ----
static constexpr int PBUF = 36*48*8;   // u16 per staging buffer

DEVI void cp16(const u16* g, u16* l) {
#if __has_builtin(__builtin_amdgcn_global_load_lds)
  __builtin_amdgcn_global_load_lds(
      (const __attribute__((address_space(1))) uint32_t*)g,
      (__attribute__((address_space(3))) uint32_t*)l, 16, 0, 0);
#else
  *(uint4*)l = *(const uint4*)g;
#endif
}

DEVI void stage(const u16* __restrict__ satT, int m, int cb, int y0, int x0,
                int tid, u16* dst) {
  const size_t rowbase = ((size_t)(m*4 + cb) * 96 + y0) * 96;
  #pragma unroll
  for (int it = 0; it < 7; ++it) {
    const int k = it*256 + tid;
    if (k < 1728) {
      const int rho = k / 48;
      const int px  = k - rho*48;
      int X = x0 + px; if (X > 95) X = 95;   // clamped feeds only x>=65 (never stored)
      cp16(satT + (rowbase + (size_t)rho*96 + X)*8, dst + (size_t)k*8);
    }
  }
}

__global__ __launch_bounds__(256, 4) void k_conv(
    const u16* __restrict__ satT, const u16* __restrict__ gP,
    const float* __restrict__ part, const float* __restrict__ nrm,
    const int* __restrict__ tm, u32* __restrict__ simenc,
    float* __restrict__ vdiag)
{
  __shared__ __align__(16) u16 patch[2*PBUF];   // 55296 B

  int bi = blockIdx.x;
  const int xt = bi % 5; bi /= 5;
  const int yt = bi % 13;
  const int m  = bi / 13;
  const int y0 = yt*5, x0 = xt*16;
  const int tid = threadIdx.x;
  const int wave = tid >> 6, lane = tid & 63;
  const int pr = lane & 15, q = lane >> 4;

  stage(satT, m, 0, y0, x0, tid, patch);
  asm volatile("s_waitcnt vmcnt(0)" ::: "memory");
  __syncthreads();

  floatx4 acc[5];
  #pragma unroll
  for (int r = 0; r < 5; ++r) acc[r] = (floatx4){0.f, 0.f, 0.f, 0.f};

  #pragma unroll 1
  for (int cb = 0; cb < 4; ++cb) {
    const u16* cur = patch + (size_t)(cb & 1)*PBUF;
    if (cb < 3) stage(satT, m, cb+1, y0, x0, tid, patch + (size_t)((cb+1)&1)*PBUF);

    #pragma unroll
    for (int jbi = 0; jbi < 2; ++jbi) {
      const int jb = wave*2 + jbi;
      const int apx = pr + jb*4 + q;
      const u16* bp = gP + ((size_t)cb*1024 + (size_t)(jb*4+q))*128 + (size_t)pr*8;

      uint4 Br[4];
      #pragma unroll
      for (int ii = 0; ii < 4; ++ii) Br[ii] = *(const uint4*)(bp + (size_t)ii*4096);
      uint4 Ah[8];
      #pragma unroll
      for (int s = 0; s < 6; ++s) Ah[s] = *(const uint4*)(&cur[((size_t)s*48 + apx)*8]);

      #pragma unroll
      for (int i = 0; i < 32; ++i) {
        if (i < 30)
          Ah[(i+6)&7] = *(const uint4*)(&cur[((size_t)(i+6)*48 + apx)*8]);
        const bf16x8 bf = __builtin_bit_cast(bf16x8, Br[i&3]);
        if (i < 28)
          Br[(i+4)&3] = *(const uint4*)(bp + (size_t)(i+4)*4096);
        #pragma unroll
        for (int r = 0; r < 5; ++r)
          acc[r] = __builtin_amdgcn_mfma_f32_16x16x32_bf16(
              __builtin_bit_cast(bf16x8, Ah[(i+r)&7]), bf, acc[r], 0, 0, 0);
      }
    }
    __syncthreads();   // all waves done with cur; drains next-buffer staging
  }

  // combine hi (cols 0-7) + lo (cols 8-15)
  float vals[20];
  #pragma unroll
  for (int r = 0; r < 5; ++r)
    #pragma unroll
    for (int e = 0; e < 4; ++e)
      vals[r*4+e] = acc[r][e] + __shfl_xor(acc[r][e], 8);

  float* red = (float*)patch;        // 4*64*21*4 = 21504 B (buf0 region)
  #pragma unroll
  for (int u = 0; u < 20; ++u) red[((size_t)wave*64 + lane)*21 + u] = vals[u];
  __syncthreads();

  if (wave == 0) {
    const int n = pr;
    const bool act = (n < 8);
    const float srn = 1.f / fmaxf(sqrtf(nrm[8+m]), 1e-12f);
    const float grn = 1.f / fmaxf(sqrtf(nrm[n & 7]), 1e-12f);
    const float cscale = grn * srn, pscale = srn * srn;
    const int method = tm[0];
    float mv = -3.4e38f;
    #pragma unroll
    for (int r = 0; r < 5; ++r) {
      #pragma unroll
      for (int e = 0; e < 4; ++e) {
        const int x = x0 + q*4 + e;
        if (act && x < 65) {
          float s = 0.f;
          #pragma unroll
          for (int w = 0; w < 4; ++w) s += red[((size_t)w*64 + lane)*21 + r*4 + e];
          const float pt = part[(size_t)m*4225 + (size_t)(y0+r)*65 + x] * pscale;
          float denom = (method == 0) ? sqrtf(pt) : pt;
          denom = fmaxf(denom, 1e-12f);
          const float v = s * cscale / denom;
          if (n == m) vdiag[(size_t)m*4225 + (size_t)(y0+r)*65 + x] = v;
          mv = fmaxf(mv, v);
        }
      }
    }
    mv = fmaxf(mv, __shfl_xor(mv, 16));
    mv = fmaxf(mv, __shfl_xor(mv, 32));
    if (act && q == 0) atomicMax(&simenc[m*8 + n], encf(mv));
  }
}

// ---- K4: blocks 0-7: diag candidate collect + exact fp32 refine + mask; block 8: sim decode ----
__global__ void k_post(const float* __restrict__ vdiag, const u32* __restrict__ simenc,
                       const float* __restrict__ grd, const float* __restrict__ sat,
                       const float* __restrict__ part, const float* __restrict__ nrm,
                       const int* __restrict__ tm, const float* __restrict__ gmask,
                       float* __restrict__ out) {
  const int t = threadIdx.x;
  if (blockIdx.x == 8) {
    if (t < 64) out[t] = decf(simenc[t]);
    return;
  }
  const int n = blockIdx.x;
  __shared__ float red[256];
  __shared__ int cands[64];
  __shared__ int ccnt;
  __shared__ float sbest; __shared__ int sbix;
  __shared__ int sph, spw;

  const float* vd = vdiag + (size_t)n*4225;
  float mv = -3.4e38f;
  for (int idx = t; idx < 4225; idx += 256) mv = fmaxf(mv, vd[idx]);
  red[t] = mv; __syncthreads();
  for (int s = 128; s > 0; s >>= 1) { if (t < s) red[t] = fmaxf(red[t], red[t+s]); __syncthreads(); }
  const float vmax = red[0];
  if (t == 0) { ccnt = 0; sbest = -3.4e38f; sbix = 0x7FFFFFFF; }
  __syncthreads();
  const float thr = vmax - 3e-3f;     // >> 2x split error (~1e-3)
  for (int idx = t; idx < 4225; idx += 256)
    if (vd[idx] >= thr) { const int s = atomicAdd(&ccnt, 1); if (s < 64) cands[s] = idx; }
  __syncthreads();
  int nc = ccnt; if (nc > 64) nc = 64; if (nc < 1) nc = 1;

  const float srn = 1.f / fmaxf(sqrtf(nrm[8+n]), 1e-12f);
  const float grn = 1.f / fmaxf(sqrtf(nrm[n]), 1e-12f);
  const float cscale = grn * srn, pscale = srn * srn;
  const int method = tm[0];
  const int c = t >> 3, s8 = t & 7;
  for (int ci = 0; ci < nc; ++ci) {
    const int idx = cands[ci];
    const int y = idx / 65, x = idx - y*65;
    float a = 0.f;
    #pragma unroll
    for (int ii = 0; ii < 4; ++ii) {
      const int i = s8 + ii*8;
      const float* gr = grd + ((size_t)n*32 + c)*1024 + i*32;
      const float* sr = sat + (((size_t)n*32 + c)*128 + (16 + y + i))*128 + (16 + x);
      #pragma unroll
      for (int j = 0; j < 32; ++j) a += gr[j] * sr[j];
    }
    red[t] = a; __syncthreads();
    for (int st = 128; st > 0; st >>= 1) { if (t < st) red[t] += red[t+st]; __syncthreads(); }
    if (t == 0) {
      const float pt = part[(size_t)n*4225 + idx] * pscale;
      float denom = (method == 0) ? sqrtf(pt) : pt;
      denom = fmaxf(denom, 1e-12f);
      const float v = red[0] * cscale / denom;
      if (v > sbest || (v == sbest && idx < sbix)) { sbest = v; sbix = idx; }
    }
    __syncthreads();
  }
  if (t == 0) { sph = sbix / 65; spw = sbix - (sbix/65)*65; }
  __syncthreads();
  const int ph = sph, pw = spw;
  for (int p = t; p < 1024; p += 256)
    out[64 + (size_t)n*9216 + (size_t)(ph + (p>>5))*96 + (pw + (p&31))] = gmask[n*1024 + p];
}

extern "C" void kernel_launch(void* const* d_in, const int* in_sizes, int n_in,
                              void* d_out, int out_size, void* d_ws, size_t ws_size,
                              hipStream_t stream) {
  const float* grd = (const float*)d_in[0];
  const float* sat = (const float*)d_in[1];
  const int*   tm  = (const int*)d_in[2];
  float* out = (float*)d_out;
  char* ws = (char*)d_ws;

  u16*   sTh   = (u16*)(ws + OFF_SATT);
  u16*   gP    = (u16*)(ws + OFF_GRDP);
  float* s2    = (float*)(ws + OFF_S2);
  float* part  = (float*)(ws + OFF_PART);
  float* nrm   = (float*)(ws + OFF_NRM);
  u32*   sim   = (u32*)(ws + OFF_SIM);
  float* vdiag = (float*)(ws + OFF_VDIAG);
  float* gmask = (float*)(ws + OFF_MASK);

  hipMemsetAsync(d_out, 0, (size_t)out_size * sizeof(float), stream);
  hipMemsetAsync(nrm, 0, 64 + 256, stream);   // nrm[16] + sim[64]

  k_prep<<<392, 256, 0, stream>>>(grd, sat, sTh, gP, s2, nrm, gmask);
  k_win <<<104, 256, 0, stream>>>(s2, part);
  k_conv<<<520, 256, 0, stream>>>(sTh, gP, part, nrm, tm, sim, vdiag);
  k_post<<<9,   256, 0, stream>>>(vdiag, sim, grd, sat, part, nrm, tm, gmask, out);
}

// Round 5
// 202.985 us; speedup vs baseline: 1.0739x; 1.0739x over previous
//
#include <hip/hip_runtime.h>
#include <stdint.h>

typedef unsigned short u16;
typedef unsigned int u32;
typedef __bf16 bf16x8 __attribute__((ext_vector_type(8)));
typedef float floatx4 __attribute__((ext_vector_type(4)));

#define DEVI static __device__ __forceinline__

DEVI u16 f2bf(float f) {
  uint32_t u = __builtin_bit_cast(uint32_t, f);
  u += 0x7FFFu + ((u >> 16) & 1u);
  return (u16)(u >> 16);
}
DEVI float bf2f(u16 b) { return __builtin_bit_cast(float, (uint32_t)b << 16); }

// ---- workspace layout (bytes) ----
static constexpr size_t OFF_CORR  = 0;                                  // f32 [m][n][65][65] 1.08MB (memset 0)
static constexpr size_t OFF_NRM   = OFF_CORR + (size_t)270400*4;        // f32 grd_nrm2[8], sat_nrm2[8] (memset 0)
static constexpr size_t OFF_SATT  = OFF_NRM + 64;                       // bf16 [m][cb][y][x][c8] 4.72MB
static constexpr size_t OFF_GRDP  = OFF_SATT + (size_t)8*4*96*96*8*2;   // bf16 [cb][i*32+j][col16][c8] 1.05MB
static constexpr size_t OFF_S2    = OFF_GRDP + (size_t)4*1024*16*8*2;   // f32 [8][96][96]
static constexpr size_t OFF_PART  = OFF_S2   + (size_t)73728*4;         // f32 [8][65][65]
static constexpr size_t OFF_CNT   = OFF_PART + (size_t)33800*4;         // int cnt[8]
static constexpr size_t OFF_CAND  = OFF_CNT  + 32;                      // int cand[8][64]
static constexpr size_t OFF_MASK  = OFF_CAND + 2048;                    // f32 [8][1024]

// ---- K1: prep. blocks 0..383: sat -> bf16 channels-last (coalesced via LDS transpose)
//          blocks 384..391: grd -> packed hi|lo cols + norm + channel-sum mask.
__global__ void k_prep(const float* __restrict__ grd, const float* __restrict__ sat,
                       u16* __restrict__ sTh, u16* __restrict__ gP,
                       float* __restrict__ s2, float* __restrict__ nrm,
                       float* __restrict__ gmask) {
  __shared__ float L[2*32*97];
  __shared__ float red[256];
  const int t = threadIdx.x;
  if (blockIdx.x < 384) {
    const int m  = blockIdx.x / 48;
    const int yp = blockIdx.x - (blockIdx.x / 48) * 48;
    #pragma unroll
    for (int k = 0; k < 6; ++k) {
      const int idx = k*256 + t;
      const int row = idx / 768;
      const int r2  = idx - row*768;
      const int c   = r2 / 24;
      const int xq  = r2 - c*24;
      const int y   = yp*2 + row;
      const float4 v = *(const float4*)(sat + (((size_t)m*32 + c)*128 + (16+y))*128 + 16 + xq*4);
      float* Lp = &L[(row*32 + c)*97 + xq*4];
      Lp[0]=v.x; Lp[1]=v.y; Lp[2]=v.z; Lp[3]=v.w;
    }
    __syncthreads();
    float ss = 0.f;
    if (t < 192) {
      const int row = t / 96, x = t - (t/96)*96;
      #pragma unroll
      for (int c = 0; c < 32; ++c) { const float v = L[(row*32+c)*97 + x]; ss += v*v; }
      s2[(size_t)m*9216 + (yp*2+row)*96 + x] = ss;
    }
    red[t] = ss; __syncthreads();
    for (int s = 128; s > 0; s >>= 1) { if (t < s) red[t] += red[t+s]; __syncthreads(); }
    if (t == 0) atomicAdd(&nrm[8+m], red[0]);
    #pragma unroll
    for (int k = 0; k < 3; ++k) {
      const int o   = k*256 + t;
      const int row = o / 384;
      const int r2  = o - row*384;
      const int cb  = r2 / 96;
      const int x   = r2 - cb*96;
      union { u16 us[8]; uint4 v4; } P;
      #pragma unroll
      for (int e = 0; e < 8; ++e) P.us[e] = f2bf(L[(row*32 + cb*8 + e)*97 + x]);
      *(uint4*)(&sTh[(((size_t)m*4+cb)*9216 + (size_t)(yp*2+row)*96 + x)*8]) = P.v4;
    }
  } else {
    const int n = blockIdx.x - 384;
    float nn = 0.f, scs[4];
    #pragma unroll
    for (int it = 0; it < 4; ++it) {
      const int pidx = it*256 + t;
      float vals[32]; float sc = 0.f;
      #pragma unroll
      for (int c = 0; c < 32; ++c) {
        const float v = grd[((size_t)n*32 + c)*1024 + pidx];
        vals[c] = v; sc += v; nn += v*v;
      }
      scs[it] = sc;
      #pragma unroll
      for (int cb = 0; cb < 4; ++cb) {
        union { u16 us[8]; uint4 v4; } ph, pl;
        #pragma unroll
        for (int e = 0; e < 8; ++e) {
          const float v = vals[cb*8+e];
          const u16 h = f2bf(v); ph.us[e] = h; pl.us[e] = f2bf(v - bf2f(h));
        }
        const size_t o = ((size_t)cb*1024 + pidx)*128;
        *(uint4*)(&gP[o + (size_t)n*8])     = ph.v4;
        *(uint4*)(&gP[o + (size_t)(n+8)*8]) = pl.v4;
      }
    }
    red[t] = nn; __syncthreads();
    for (int s = 128; s > 0; s >>= 1) { if (t < s) red[t] += red[t+s]; __syncthreads(); }
    const float gn = fmaxf(sqrtf(red[0]), 1e-12f);
    if (t == 0) nrm[n] = red[0];
    const float thr = 1e-6f * gn;
    #pragma unroll
    for (int it = 0; it < 4; ++it)
      gmask[n*1024 + it*256 + t] = (fabsf(scs[it]) > thr) ? 1.f : 0.f;
  }
}

// ---- K2: 32x32 window sum of s2; grid 104 = (m, 5-row slab) ----
__global__ void k_win(const float* __restrict__ s2, float* __restrict__ part) {
  __shared__ float hs[36*65];
  const int b = blockIdx.x, t = threadIdx.x;
  const int m = b / 13, yt = b - (b/13)*13;
  const int ybase = yt * 5;
  const float* sp = s2 + (size_t)m*9216;
  for (int idx = t; idx < 36*65; idx += 256) {
    const int rho = idx / 65, xo = idx - rho*65;
    const float* r = sp + (ybase + rho)*96 + xo;
    float s = 0.f;
    #pragma unroll
    for (int j = 0; j < 32; ++j) s += r[j];
    hs[idx] = s;
  }
  __syncthreads();
  for (int idx = t; idx < 5*65; idx += 256) {
    const int yo = idx / 65, xo = idx - yo*65;
    float s = 0.f;
    #pragma unroll
    for (int i = 0; i < 32; ++i) s += hs[(yo+i)*65 + xo];
    part[(size_t)m*4225 + (size_t)(ybase+yo)*65 + xo] = s;
  }
}

// ---- K3: conv. grid 2080 = (m,yt13,xt5,cb4); block = 4 waves splitting j (2 jb each).
// 2-term split: A = sat-hi (LDS patch), B = packed [grd-hi | grd-lo] in 16 cols.
// Br ring depth 8 (covers L2 ~200cyc): init rows 0-7, i<24 prefetch row i+8.
// Ah ring: round-2-verified schedule — init rows 0-5, i<30 prefetch row i+6 (rows 6..35 ALL covered;
// round 4's i<25/row i+7 variant left rows 32-35 stale -> wrong argmax).
// cb partials atomicAdd'ed into one corr plane.
__global__ __launch_bounds__(256, 4) void k_conv(
    const u16* __restrict__ satT, const u16* __restrict__ gP,
    float* __restrict__ corr)
{
  __shared__ __align__(16) u16 patch[36*48*8];   // 27648 B, sat-hi [rho][px][c8]

  int bi = blockIdx.x;
  const int cb = bi & 3; bi >>= 2;
  const int xt = bi % 5; bi /= 5;
  const int yt = bi % 13;
  const int m  = bi / 13;
  const int y0 = yt*5, x0 = xt*16;
  const int tid = threadIdx.x;
  const int wave = tid >> 6, lane = tid & 63;

  {
    const size_t rowbase = ((size_t)(m*4 + cb) * 96 + y0) * 96;
    for (int k = tid; k < 36*48; k += 256) {
      const int rho = k / 48;
      const int px  = k - rho*48;
      int X = x0 + px; if (X > 95) X = 95;     // clamped feeds only x>=65 (never stored)
      *(uint4*)(&patch[(size_t)k*8]) = *(const uint4*)(&satT[(rowbase + (size_t)rho*96 + X)*8]);
    }
  }
  __syncthreads();

  const int pr = lane & 15;       // A row (x-offset) == B col
  const int q  = lane >> 4;

  floatx4 acc[5];
  #pragma unroll
  for (int r = 0; r < 5; ++r) acc[r] = (floatx4){0.f, 0.f, 0.f, 0.f};

  #pragma unroll
  for (int jbi = 0; jbi < 2; ++jbi) {
    const int jb = wave*2 + jbi;
    const int apx = pr + jb*4 + q;                         // <= 46
    const u16* bp = gP + ((size_t)cb*1024 + (size_t)(jb*4+q))*128 + (size_t)pr*8;

    uint4 Br[8];
    #pragma unroll
    for (int ii = 0; ii < 8; ++ii) Br[ii] = *(const uint4*)(bp + (size_t)ii*4096);
    uint4 Ah[8];
    #pragma unroll
    for (int s = 0; s < 6; ++s) Ah[s] = *(const uint4*)(&patch[((size_t)s*48 + apx)*8]);

    #pragma unroll
    for (int i = 0; i < 32; ++i) {
      if (i < 30)
        Ah[(i+6)&7] = *(const uint4*)(&patch[((size_t)(i+6)*48 + apx)*8]);
      const bf16x8 bf = __builtin_bit_cast(bf16x8, Br[i&7]);
      if (i < 24)
        Br[(i+8)&7] = *(const uint4*)(bp + (size_t)(i+8)*4096);
      #pragma unroll
      for (int r = 0; r < 5; ++r)
        acc[r] = __builtin_amdgcn_mfma_f32_16x16x32_bf16(
            __builtin_bit_cast(bf16x8, Ah[(i+r)&7]), bf, acc[r], 0, 0, 0);
    }
  }

  // combine hi (cols 0-7) + lo (cols 8-15): partner lane differs in bit 3
  float vals[20];
  #pragma unroll
  for (int r = 0; r < 5; ++r)
    #pragma unroll
    for (int e = 0; e < 4; ++e)
      vals[r*4+e] = acc[r][e] + __shfl_xor(acc[r][e], 8);

  // cross-wave K-sum (4 waves = j-octets) via LDS, then wave 0 atomicAdds cb-partial
  __syncthreads();
  float* red = (float*)patch;                    // 4*64*21*4 = 21504 B <= 27648
  #pragma unroll
  for (int u = 0; u < 20; ++u) red[((size_t)wave*64 + lane)*21 + u] = vals[u];
  __syncthreads();
  if (wave == 0 && pr < 8) {
    #pragma unroll
    for (int r = 0; r < 5; ++r) {
      #pragma unroll
      for (int e = 0; e < 4; ++e) {
        const int x = x0 + q*4 + e;
        if (x < 65) {
          float s = 0.f;
          #pragma unroll
          for (int w = 0; w < 4; ++w) s += red[((size_t)w*64 + lane)*21 + r*4 + e];
          atomicAdd(&corr[((size_t)(m*8+pr)*65 + (y0+r))*65 + x], s);
        }
      }
    }
  }
}

// ---- K4: normalize, per-(m,n) max -> similarity; diag: collect candidates near max ----
__global__ void k_reduce(const float* __restrict__ corr, const float* __restrict__ part,
                         const float* __restrict__ nrm, const int* __restrict__ tm,
                         float* __restrict__ out, int* __restrict__ cnt,
                         int* __restrict__ cand) {
  __shared__ float vbuf[4225];
  __shared__ float bv[256];
  __shared__ int ccnt;
  const int mb = blockIdx.x;
  const int m = mb >> 3, n = mb & 7, t = threadIdx.x;
  const float srn = 1.f / fmaxf(sqrtf(nrm[8 + m]), 1e-12f);
  const float grn = 1.f / fmaxf(sqrtf(nrm[n]), 1e-12f);
  const int method = tm[0];
  const float cscale = grn * srn, pscale = srn * srn;
  const float* cp = corr + (size_t)(m*8+n)*4225;
  const float* pp = part + (size_t)m*4225;
  const bool diag = (m == n);
  if (t == 0) ccnt = 0;
  float bestv = -3.4e38f;
  for (int idx = t; idx < 4225; idx += 256) {
    const float partical = pp[idx] * pscale;
    float denom = (method == 0) ? sqrtf(partical) : partical;
    denom = fmaxf(denom, 1e-12f);
    const float v = cp[idx] * cscale / denom;
    if (diag) vbuf[idx] = v;
    bestv = fmaxf(bestv, v);
  }
  bv[t] = bestv; __syncthreads();
  for (int s = 128; s > 0; s >>= 1) {
    if (t < s) bv[t] = fmaxf(bv[t], bv[t+s]);
    __syncthreads();
  }
  if (t == 0) out[m*8+n] = bv[0];
  if (diag) {
    const float thr = bv[0] - 3e-3f;     // >> 2-term split error (~1e-5) + atomic-order noise
    for (int idx = t; idx < 4225; idx += 256)
      if (vbuf[idx] >= thr) {
        const int s = atomicAdd(&ccnt, 1);
        if (s < 64) cand[n*64 + s] = idx;
      }
    __syncthreads();
    if (t == 0) cnt[n] = ccnt;
  }
}

// ---- K5: exact fp32 re-dot of diag candidates, true argmax, mask scatter ----
__global__ void k_refine(const float* __restrict__ grd, const float* __restrict__ sat,
                         const float* __restrict__ part, const float* __restrict__ nrm,
                         const int* __restrict__ tm, const int* __restrict__ cnt,
                         const int* __restrict__ cand, const float* __restrict__ gmask,
                         float* __restrict__ out) {
  const int n = blockIdx.x, t = threadIdx.x;
  const float srn = 1.f / fmaxf(sqrtf(nrm[8 + n]), 1e-12f);
  const float grn = 1.f / fmaxf(sqrtf(nrm[n]), 1e-12f);
  const float cscale = grn * srn, pscale = srn * srn;
  const int method = tm[0];
  int nc = cnt[n]; if (nc > 64) nc = 64; if (nc < 1) nc = 1;
  __shared__ float red[256];
  __shared__ float sbest; __shared__ int sbix;
  __shared__ int sph, spw;
  if (t == 0) { sbest = -3.4e38f; sbix = 0x7FFFFFFF; }
  __syncthreads();
  const int c = t >> 3, s8 = t & 7;
  for (int ci = 0; ci < nc; ++ci) {
    const int idx = cand[n*64 + ci];
    const int y = idx / 65, x = idx - y*65;
    float a = 0.f;
    #pragma unroll
    for (int ii = 0; ii < 4; ++ii) {
      const int i = s8 + ii*8;
      const float* gr = grd + ((size_t)n*32 + c)*1024 + i*32;
      const float* sr = sat + (((size_t)n*32 + c)*128 + (16 + y + i))*128 + (16 + x);
      #pragma unroll
      for (int j = 0; j < 32; ++j) a += gr[j] * sr[j];
    }
    red[t] = a; __syncthreads();
    for (int st = 128; st > 0; st >>= 1) {
      if (t < st) red[t] += red[t+st];
      __syncthreads();
    }
    if (t == 0) {
      const float pt = part[(size_t)n*4225 + idx] * pscale;
      float denom = (method == 0) ? sqrtf(pt) : pt;
      denom = fmaxf(denom, 1e-12f);
      const float v = red[0] * cscale / denom;
      if (v > sbest || (v == sbest && idx < sbix)) { sbest = v; sbix = idx; }
    }
    __syncthreads();
  }
  if (t == 0) { sph = sbix / 65; spw = sbix - (sbix/65)*65; }
  __syncthreads();
  const int ph = sph, pw = spw;
  for (int p = t; p < 1024; p += 256)
    out[64 + (size_t)n*9216 + (size_t)(ph + (p>>5))*96 + (pw + (p&31))] = gmask[n*1024 + p];
}

extern "C" void kernel_launch(void* const* d_in, const int* in_sizes, int n_in,
                              void* d_out, int out_size, void* d_ws, size_t ws_size,
                              hipStream_t stream) {
  const float* grd = (const float*)d_in[0];
  const float* sat = (const float*)d_in[1];
  const int*   tm  = (const int*)d_in[2];
  float* out = (float*)d_out;
  char* ws = (char*)d_ws;

  float* corr  = (float*)(ws + OFF_CORR);
  float* nrm   = (float*)(ws + OFF_NRM);
  u16*   sTh   = (u16*)(ws + OFF_SATT);
  u16*   gP    = (u16*)(ws + OFF_GRDP);
  float* s2    = (float*)(ws + OFF_S2);
  float* part  = (float*)(ws + OFF_PART);
  int*   cnt   = (int*)(ws + OFF_CNT);
  int*   cand  = (int*)(ws + OFF_CAND);
  float* gmask = (float*)(ws + OFF_MASK);

  hipMemsetAsync(d_out, 0, (size_t)out_size * sizeof(float), stream);
  hipMemsetAsync(corr, 0, (size_t)270400*4 + 64, stream);   // corr + nrm (contiguous)

  k_prep  <<<392,  256, 0, stream>>>(grd, sat, sTh, gP, s2, nrm, gmask);
  k_win   <<<104,  256, 0, stream>>>(s2, part);
  k_conv  <<<2080, 256, 0, stream>>>(sTh, gP, corr);
  k_reduce<<<64,   256, 0, stream>>>(corr, part, nrm, tm, out, cnt, cand);
  k_refine<<<8,    256, 0, stream>>>(grd, sat, part, nrm, tm, cnt, cand, gmask, out);
}

// Round 6
// 170.827 us; speedup vs baseline: 1.2760x; 1.1883x over previous
//
#include <hip/hip_runtime.h>
#include <stdint.h>

typedef unsigned short u16;
typedef unsigned int u32;
typedef __bf16 bf16x8 __attribute__((ext_vector_type(8)));
typedef float floatx4 __attribute__((ext_vector_type(4)));

#define DEVI static __device__ __forceinline__

DEVI u16 f2bf(float f) {
  uint32_t u = __builtin_bit_cast(uint32_t, f);
  u += 0x7FFFu + ((u >> 16) & 1u);
  return (u16)(u >> 16);
}
DEVI float bf2f(u16 b) { return __builtin_bit_cast(float, (uint32_t)b << 16); }

// ---- workspace layout (bytes) ----
static constexpr size_t OFF_CORRP = 0;                                   // f32 [cb4][m][n][65][65] 4.33MB
static constexpr size_t OFF_SATT  = OFF_CORRP + (size_t)4*270400*4;      // bf16 [m][cb][y][x][c8] 4.72MB
static constexpr size_t OFF_GRDP  = OFF_SATT + (size_t)8*4*96*96*8*2;    // bf16 [cb][i*32+j][col16][c8] 1.05MB
static constexpr size_t OFF_S2    = OFF_GRDP + (size_t)4*1024*16*8*2;    // f32 [8][96][96]
static constexpr size_t OFF_NRMP  = OFF_S2   + (size_t)73728*4;          // f32 sat nrm partials [8][48]
static constexpr size_t OFF_GNRM  = OFF_NRMP + 8*48*4;                   // f32 grd nrm2 [8]
static constexpr size_t OFF_MASK  = OFF_GNRM + 32;                       // f32 [8][1024]

// ---- K1: prep. blocks 0..383: sat -> bf16 channels-last (LDS transpose) + s2 + norm partial.
//          blocks 384..391: grd -> packed hi|lo cols + norm + channel-sum mask.
__global__ void k_prep(const float* __restrict__ grd, const float* __restrict__ sat,
                       u16* __restrict__ sTh, u16* __restrict__ gP,
                       float* __restrict__ s2, float* __restrict__ nrmp,
                       float* __restrict__ gnrm, float* __restrict__ gmask) {
  __shared__ float L[2*32*97];
  __shared__ float red[256];
  const int t = threadIdx.x;
  if (blockIdx.x < 384) {
    const int m  = blockIdx.x / 48;
    const int yp = blockIdx.x - (blockIdx.x / 48) * 48;
    #pragma unroll
    for (int k = 0; k < 6; ++k) {
      const int idx = k*256 + t;
      const int row = idx / 768;
      const int r2  = idx - row*768;
      const int c   = r2 / 24;
      const int xq  = r2 - c*24;
      const int y   = yp*2 + row;
      const float4 v = *(const float4*)(sat + (((size_t)m*32 + c)*128 + (16+y))*128 + 16 + xq*4);
      float* Lp = &L[(row*32 + c)*97 + xq*4];
      Lp[0]=v.x; Lp[1]=v.y; Lp[2]=v.z; Lp[3]=v.w;
    }
    __syncthreads();
    float ss = 0.f;
    if (t < 192) {
      const int row = t / 96, x = t - (t/96)*96;
      #pragma unroll
      for (int c = 0; c < 32; ++c) { const float v = L[(row*32+c)*97 + x]; ss += v*v; }
      s2[(size_t)m*9216 + (yp*2+row)*96 + x] = ss;
    }
    red[t] = ss; __syncthreads();
    for (int s = 128; s > 0; s >>= 1) { if (t < s) red[t] += red[t+s]; __syncthreads(); }
    if (t == 0) nrmp[m*48 + yp] = red[0];
    #pragma unroll
    for (int k = 0; k < 3; ++k) {
      const int o   = k*256 + t;
      const int row = o / 384;
      const int r2  = o - row*384;
      const int cb  = r2 / 96;
      const int x   = r2 - cb*96;
      union { u16 us[8]; uint4 v4; } P;
      #pragma unroll
      for (int e = 0; e < 8; ++e) P.us[e] = f2bf(L[(row*32 + cb*8 + e)*97 + x]);
      *(uint4*)(&sTh[(((size_t)m*4+cb)*9216 + (size_t)(yp*2+row)*96 + x)*8]) = P.v4;
    }
  } else {
    const int n = blockIdx.x - 384;
    float nn = 0.f, scs[4];
    #pragma unroll
    for (int it = 0; it < 4; ++it) {
      const int pidx = it*256 + t;
      float vals[32]; float sc = 0.f;
      #pragma unroll
      for (int c = 0; c < 32; ++c) {
        const float v = grd[((size_t)n*32 + c)*1024 + pidx];
        vals[c] = v; sc += v; nn += v*v;
      }
      scs[it] = sc;
      #pragma unroll
      for (int cb = 0; cb < 4; ++cb) {
        union { u16 us[8]; uint4 v4; } ph, pl;
        #pragma unroll
        for (int e = 0; e < 8; ++e) {
          const float v = vals[cb*8+e];
          const u16 h = f2bf(v); ph.us[e] = h; pl.us[e] = f2bf(v - bf2f(h));
        }
        const size_t o = ((size_t)cb*1024 + pidx)*128;
        *(uint4*)(&gP[o + (size_t)n*8])     = ph.v4;
        *(uint4*)(&gP[o + (size_t)(n+8)*8]) = pl.v4;
      }
    }
    red[t] = nn; __syncthreads();
    for (int s = 128; s > 0; s >>= 1) { if (t < s) red[t] += red[t+s]; __syncthreads(); }
    const float gn = fmaxf(sqrtf(red[0]), 1e-12f);
    if (t == 0) gnrm[n] = red[0];
    const float thr = 1e-6f * gn;
    #pragma unroll
    for (int it = 0; it < 4; ++it)
      gmask[n*1024 + it*256 + t] = (fabsf(scs[it]) > thr) ? 1.f : 0.f;
  }
}

// ---- K2: conv. grid 2080 = (m,yt13,xt5,cb4); block = 4 waves splitting j (2 jb each).
// 2-term split: A = sat-hi (LDS patch), B = packed [grd-hi | grd-lo] in 16 cols.
// Br ring depth 8 (covers L2 ~200cyc). Ah ring: round-2-verified schedule
// (init rows 0-5, i<30 prefetch row i+6 — rows 6..35 all covered).
// Plane stores per cb (NO atomics — device-scope RMW tripled WRITE_SIZE in r5).
__global__ __launch_bounds__(256, 4) void k_conv(
    const u16* __restrict__ satT, const u16* __restrict__ gP,
    float* __restrict__ corr_p)
{
  __shared__ __align__(16) u16 patch[36*48*8];   // 27648 B

  int bi = blockIdx.x;
  const int cb = bi & 3; bi >>= 2;
  const int xt = bi % 5; bi /= 5;
  const int yt = bi % 13;
  const int m  = bi / 13;
  const int y0 = yt*5, x0 = xt*16;
  const int tid = threadIdx.x;
  const int wave = tid >> 6, lane = tid & 63;

  {
    const size_t rowbase = ((size_t)(m*4 + cb) * 96 + y0) * 96;
    for (int k = tid; k < 36*48; k += 256) {
      const int rho = k / 48;
      const int px  = k - rho*48;
      int X = x0 + px; if (X > 95) X = 95;     // clamped feeds only x>=65 (never stored)
      *(uint4*)(&patch[(size_t)k*8]) = *(const uint4*)(&satT[(rowbase + (size_t)rho*96 + X)*8]);
    }
  }
  __syncthreads();

  const int pr = lane & 15;       // A row (x-offset) == B col
  const int q  = lane >> 4;

  floatx4 acc[5];
  #pragma unroll
  for (int r = 0; r < 5; ++r) acc[r] = (floatx4){0.f, 0.f, 0.f, 0.f};

  #pragma unroll
  for (int jbi = 0; jbi < 2; ++jbi) {
    const int jb = wave*2 + jbi;
    const int apx = pr + jb*4 + q;                         // <= 46
    const u16* bp = gP + ((size_t)cb*1024 + (size_t)(jb*4+q))*128 + (size_t)pr*8;

    uint4 Br[8];
    #pragma unroll
    for (int ii = 0; ii < 8; ++ii) Br[ii] = *(const uint4*)(bp + (size_t)ii*4096);
    uint4 Ah[8];
    #pragma unroll
    for (int s = 0; s < 6; ++s) Ah[s] = *(const uint4*)(&patch[((size_t)s*48 + apx)*8]);

    #pragma unroll
    for (int i = 0; i < 32; ++i) {
      if (i < 30)
        Ah[(i+6)&7] = *(const uint4*)(&patch[((size_t)(i+6)*48 + apx)*8]);
      const bf16x8 bf = __builtin_bit_cast(bf16x8, Br[i&7]);
      if (i < 24)
        Br[(i+8)&7] = *(const uint4*)(bp + (size_t)(i+8)*4096);
      #pragma unroll
      for (int r = 0; r < 5; ++r)
        acc[r] = __builtin_amdgcn_mfma_f32_16x16x32_bf16(
            __builtin_bit_cast(bf16x8, Ah[(i+r)&7]), bf, acc[r], 0, 0, 0);
    }
  }

  // combine hi (cols 0-7) + lo (cols 8-15): partner lane differs in bit 3
  float vals[20];
  #pragma unroll
  for (int r = 0; r < 5; ++r)
    #pragma unroll
    for (int e = 0; e < 4; ++e)
      vals[r*4+e] = acc[r][e] + __shfl_xor(acc[r][e], 8);

  // cross-wave K-sum via LDS, then wave 0 stores the cb-plane partial
  __syncthreads();
  float* red = (float*)patch;                    // 21504 B <= 27648
  #pragma unroll
  for (int u = 0; u < 20; ++u) red[((size_t)wave*64 + lane)*21 + u] = vals[u];
  __syncthreads();
  if (wave == 0 && pr < 8) {
    #pragma unroll
    for (int r = 0; r < 5; ++r) {
      #pragma unroll
      for (int e = 0; e < 4; ++e) {
        const int x = x0 + q*4 + e;
        if (x < 65) {
          float s = 0.f;
          #pragma unroll
          for (int w = 0; w < 4; ++w) s += red[((size_t)w*64 + lane)*21 + r*4 + e];
          corr_p[(size_t)cb*270400 + ((size_t)(m*8+pr)*65 + (y0+r))*65 + x] = s;
        }
      }
    }
  }
}

// ---- K3: fused epilogue. 64 blocks = (m,n). Window-sums in LDS, normalize,
// max -> similarity; diag blocks: candidates + exact fp32 refine + mask scatter. ----
__global__ __launch_bounds__(256) void k_post(
    const float* __restrict__ corr_p, const float* __restrict__ s2,
    const float* __restrict__ nrmp, const float* __restrict__ gnrm,
    const int* __restrict__ tm, const float* __restrict__ grd,
    const float* __restrict__ sat, const float* __restrict__ gmask,
    float* __restrict__ out)
{
  __shared__ float bufA[9216];   // s2[m], later part
  __shared__ float bufB[6240];   // hs, later v
  __shared__ float red[256];
  __shared__ int cands[64];
  __shared__ int ccnt;
  __shared__ float sbest; __shared__ int sbix;

  const int m = blockIdx.x >> 3, n = blockIdx.x & 7, t = threadIdx.x;

  // sat norm from 48 partials
  red[t] = (t < 48) ? nrmp[m*48 + t] : 0.f;
  __syncthreads();
  for (int s = 128; s > 0; s >>= 1) { if (t < s) red[t] += red[t+s]; __syncthreads(); }
  const float srn = 1.f / fmaxf(sqrtf(red[0]), 1e-12f);
  const float grn = 1.f / fmaxf(sqrtf(gnrm[n]), 1e-12f);
  const float cscale = grn * srn, pscale = srn * srn;
  const int method = tm[0];

  // phase 1: s2[m] -> bufA
  for (int idx = t; idx < 9216; idx += 256) bufA[idx] = s2[(size_t)m*9216 + idx];
  __syncthreads();
  // phase 2: horizontal 32-sum -> bufB (hs[96][65])
  for (int idx = t; idx < 6240; idx += 256) {
    const int y = idx / 65, xo = idx - y*65;
    const float* r = &bufA[y*96 + xo];
    float s = 0.f;
    #pragma unroll
    for (int j = 0; j < 32; ++j) s += r[j];
    bufB[idx] = s;
  }
  __syncthreads();
  // phase 3: vertical 32-sum -> bufA[0..4225) (part)
  for (int idx = t; idx < 4225; idx += 256) {
    const int yo = idx / 65, xo = idx - yo*65;
    float s = 0.f;
    #pragma unroll
    for (int i = 0; i < 32; ++i) s += bufB[(yo+i)*65 + xo];
    bufA[idx] = s;
  }
  __syncthreads();
  // phase 4: normalize + max; v -> bufB[0..4225)
  const float* cp = corr_p + (size_t)(m*8+n)*4225;
  float bestv = -3.4e38f;
  for (int idx = t; idx < 4225; idx += 256) {
    const float c = cp[idx] + cp[idx+270400] + cp[idx+540800] + cp[idx+811200];
    const float pt = bufA[idx] * pscale;
    float denom = (method == 0) ? sqrtf(pt) : pt;
    denom = fmaxf(denom, 1e-12f);
    const float v = c * cscale / denom;
    bufB[idx] = v;
    bestv = fmaxf(bestv, v);
  }
  __syncthreads();          // bufB fully written before reuse; red reuse below
  red[t] = bestv; __syncthreads();
  for (int s = 128; s > 0; s >>= 1) { if (t < s) red[t] = fmaxf(red[t], red[t+s]); __syncthreads(); }
  if (t == 0) out[m*8 + n] = red[0];
  if (m != n) return;
  const float vmax = red[0];

  // diag: candidate collect
  if (t == 0) { ccnt = 0; sbest = -3.4e38f; sbix = 0x7FFFFFFF; }
  __syncthreads();
  const float thr = vmax - 3e-3f;    // >> 2-term split error (~1e-5)
  for (int idx = t; idx < 4225; idx += 256)
    if (bufB[idx] >= thr) { const int s = atomicAdd(&ccnt, 1); if (s < 64) cands[s] = idx; }
  __syncthreads();
  int nc = ccnt; if (nc > 64) nc = 64; if (nc < 1) nc = 1;

  // exact fp32 re-dot of candidates
  const int c = t >> 3, s8 = t & 7;
  for (int ci = 0; ci < nc; ++ci) {
    const int idx = cands[ci];
    const int y = idx / 65, x = idx - y*65;
    float a = 0.f;
    #pragma unroll
    for (int ii = 0; ii < 4; ++ii) {
      const int i = s8 + ii*8;
      const float* gr = grd + ((size_t)n*32 + c)*1024 + i*32;
      const float* sr = sat + (((size_t)n*32 + c)*128 + (16 + y + i))*128 + (16 + x);
      #pragma unroll
      for (int j = 0; j < 32; ++j) a += gr[j] * sr[j];
    }
    red[t] = a; __syncthreads();
    for (int st = 128; st > 0; st >>= 1) { if (t < st) red[t] += red[t+st]; __syncthreads(); }
    if (t == 0) {
      const float pt = bufA[idx] * pscale;
      float denom = (method == 0) ? sqrtf(pt) : pt;
      denom = fmaxf(denom, 1e-12f);
      const float v = red[0] * cscale / denom;
      if (v > sbest || (v == sbest && idx < sbix)) { sbest = v; sbix = idx; }
    }
    __syncthreads();
  }
  const int bix = sbix;
  const int ph = bix / 65, pw = bix - (bix/65)*65;
  for (int p = t; p < 1024; p += 256)
    out[64 + (size_t)n*9216 + (size_t)(ph + (p>>5))*96 + (pw + (p&31))] = gmask[n*1024 + p];
}

extern "C" void kernel_launch(void* const* d_in, const int* in_sizes, int n_in,
                              void* d_out, int out_size, void* d_ws, size_t ws_size,
                              hipStream_t stream) {
  const float* grd = (const float*)d_in[0];
  const float* sat = (const float*)d_in[1];
  const int*   tm  = (const int*)d_in[2];
  float* out = (float*)d_out;
  char* ws = (char*)d_ws;

  float* corrp = (float*)(ws + OFF_CORRP);
  u16*   sTh   = (u16*)(ws + OFF_SATT);
  u16*   gP    = (u16*)(ws + OFF_GRDP);
  float* s2    = (float*)(ws + OFF_S2);
  float* nrmp  = (float*)(ws + OFF_NRMP);
  float* gnrm  = (float*)(ws + OFF_GNRM);
  float* gmask = (float*)(ws + OFF_MASK);

  hipMemsetAsync(d_out, 0, (size_t)out_size * sizeof(float), stream);

  k_prep<<<392,  256, 0, stream>>>(grd, sat, sTh, gP, s2, nrmp, gnrm, gmask);
  k_conv<<<2080, 256, 0, stream>>>(sTh, gP, corrp);
  k_post<<<64,   256, 0, stream>>>(corrp, s2, nrmp, gnrm, tm, grd, sat, gmask, out);
}

// Round 7
// 154.497 us; speedup vs baseline: 1.4109x; 1.1057x over previous
//
#include <hip/hip_runtime.h>
#include <stdint.h>

typedef unsigned short u16;
typedef unsigned int u32;
typedef __bf16 bf16x8 __attribute__((ext_vector_type(8)));
typedef float floatx4 __attribute__((ext_vector_type(4)));

#define DEVI static __device__ __forceinline__

DEVI u16 f2bf(float f) {
  uint32_t u = __builtin_bit_cast(uint32_t, f);
  u += 0x7FFFu + ((u >> 16) & 1u);
  return (u16)(u >> 16);
}
DEVI float bf2f(u16 b) { return __builtin_bit_cast(float, (uint32_t)b << 16); }

// ---- workspace layout (bytes) ----
static constexpr size_t OFF_CORRP = 0;                                   // f32 [cb4][m][n][65][65] 4.33MB
static constexpr size_t OFF_SATT  = OFF_CORRP + (size_t)4*270400*4;      // bf16 [m][cb][y][x][c8] 4.72MB
static constexpr size_t OFF_GRDP  = OFF_SATT + (size_t)8*4*96*96*8*2;    // bf16 [cb][i*32+j][col16][c8] 1.05MB
static constexpr size_t OFF_S2    = OFF_GRDP + (size_t)4*1024*16*8*2;    // f32 [8][96][96]
static constexpr size_t OFF_PART  = OFF_S2   + (size_t)73728*4;          // f32 [8][65][65]
static constexpr size_t OFF_NRMP  = OFF_PART + (size_t)33800*4;          // f32 sat nrm partials [8][96]
static constexpr size_t OFF_GNRM  = OFF_NRMP + 768*4;                    // f32 grd nrm2 [8]
static constexpr size_t OFF_MASK  = OFF_GNRM + 32;                       // f32 [8][1024]
static constexpr size_t OFF_VDIAG = OFF_MASK + (size_t)8192*4;           // f32 [8][65][65]
static constexpr size_t OFF_PMAX  = OFF_VDIAG + (size_t)33800*4;         // f32 [320]

// ---- K1: prep. blocks 0..767: one sat row each -> bf16 channels-last + s2 + norm partial.
//          blocks 768..775: grd -> packed hi|lo cols + norm + channel-sum mask.
__global__ __launch_bounds__(256) void k_prep(
    const float* __restrict__ grd, const float* __restrict__ sat,
    u16* __restrict__ sTh, u16* __restrict__ gP,
    float* __restrict__ s2, float* __restrict__ nrmp,
    float* __restrict__ gnrm, float* __restrict__ gmask) {
  __shared__ float L[32*100];     // [c][x] padded to 100 (float4-write conflict-free)
  __shared__ float red[256];
  const int t = threadIdx.x;
  if (blockIdx.x < 768) {
    const int m = blockIdx.x / 96, y = blockIdx.x - (blockIdx.x / 96) * 96;
    #pragma unroll
    for (int k = 0; k < 3; ++k) {          // 768 float4 loads, 3/thread, independent
      const int idx = k*256 + t;
      const int c = idx / 24, xq = idx - c*24;
      const float4 v = *(const float4*)(sat + (((size_t)m*32 + c)*128 + (16+y))*128 + 16 + xq*4);
      *(float4*)(&L[c*100 + xq*4]) = v;
    }
    __syncthreads();
    float ss = 0.f;
    if (t < 96) {
      #pragma unroll
      for (int c = 0; c < 32; ++c) { const float v = L[c*100 + t]; ss += v*v; }
      s2[(size_t)m*9216 + y*96 + t] = ss;
    }
    red[t] = ss; __syncthreads();
    for (int s = 128; s > 0; s >>= 1) { if (t < s) red[t] += red[t+s]; __syncthreads(); }
    if (t == 0) nrmp[m*96 + y] = red[0];
    for (int idx = t; idx < 384; idx += 256) {   // 4cb x 96x bf16x8 stores
      const int cb = idx / 96, x = idx - cb*96;
      union { u16 us[8]; uint4 v4; } P;
      #pragma unroll
      for (int e = 0; e < 8; ++e) P.us[e] = f2bf(L[(cb*8+e)*100 + x]);
      *(uint4*)(&sTh[(((size_t)m*4+cb)*9216 + (size_t)y*96 + x)*8]) = P.v4;
    }
  } else {
    const int n = blockIdx.x - 768;
    float nn = 0.f, scs[4];
    #pragma unroll
    for (int it = 0; it < 4; ++it) {
      const int pidx = it*256 + t;
      float vals[32]; float sc = 0.f;
      #pragma unroll
      for (int c = 0; c < 32; ++c) {
        const float v = grd[((size_t)n*32 + c)*1024 + pidx];
        vals[c] = v; sc += v; nn += v*v;
      }
      scs[it] = sc;
      #pragma unroll
      for (int cb = 0; cb < 4; ++cb) {
        union { u16 us[8]; uint4 v4; } ph, pl;
        #pragma unroll
        for (int e = 0; e < 8; ++e) {
          const float v = vals[cb*8+e];
          const u16 h = f2bf(v); ph.us[e] = h; pl.us[e] = f2bf(v - bf2f(h));
        }
        const size_t o = ((size_t)cb*1024 + pidx)*128;
        *(uint4*)(&gP[o + (size_t)n*8])     = ph.v4;
        *(uint4*)(&gP[o + (size_t)(n+8)*8]) = pl.v4;
      }
    }
    red[t] = nn; __syncthreads();
    for (int s = 128; s > 0; s >>= 1) { if (t < s) red[t] += red[t+s]; __syncthreads(); }
    const float gn = fmaxf(sqrtf(red[0]), 1e-12f);
    if (t == 0) gnrm[n] = red[0];
    const float thr = 1e-6f * gn;
    #pragma unroll
    for (int it = 0; it < 4; ++it)
      gmask[n*1024 + it*256 + t] = (fabsf(scs[it]) > thr) ? 1.f : 0.f;
  }
}

// ---- K2: blocks 0..2079: conv (m,yt13,xt5,cb4), round-2-verified MFMA core.
//          blocks 2080..2151: 32x32 window-sum of s2 -> part (m, 8-row slab).
__global__ __launch_bounds__(256, 4) void k_conv(
    const u16* __restrict__ satT, const u16* __restrict__ gP,
    const float* __restrict__ s2, float* __restrict__ corr_p,
    float* __restrict__ part)
{
  __shared__ __align__(16) u16 patch[36*48*8];   // 27648 B

  int bi = blockIdx.x;
  const int tid = threadIdx.x;

  if (bi >= 2080) {            // ---- part blocks ----
    float* S  = (float*)patch;          // [<=40][96]  15360 B
    float* HS = S + 40*96;              // [<=39][65]  10140 B  (total 25500 <= 27648)
    const int pb = bi - 2080;
    const int pm = pb / 9, ysl = (pb - pm*9)*8;
    const int nrows = (65 - ysl) < 8 ? (65 - ysl) : 8;
    const int scnt  = (96 - ysl) < 40 ? (96 - ysl) : 40;
    for (int idx = tid; idx < scnt*96; idx += 256)
      S[idx] = s2[(size_t)pm*9216 + (size_t)ysl*96 + idx];
    __syncthreads();
    const int hrows = nrows + 31;
    for (int idx = tid; idx < hrows*65; idx += 256) {
      const int r = idx / 65, xo = idx - r*65;
      const float* p = &S[r*96 + xo];
      float s = 0.f;
      #pragma unroll
      for (int j = 0; j < 32; ++j) s += p[j];
      HS[idx] = s;
    }
    __syncthreads();
    for (int idx = tid; idx < nrows*65; idx += 256) {
      const int r = idx / 65, xo = idx - r*65;
      float s = 0.f;
      #pragma unroll
      for (int i = 0; i < 32; ++i) s += HS[(r+i)*65 + xo];
      part[(size_t)pm*4225 + (size_t)(ysl+r)*65 + xo] = s;
    }
    return;
  }

  // ---- conv blocks ----
  const int cb = bi & 3; bi >>= 2;
  const int xt = bi % 5; bi /= 5;
  const int yt = bi % 13;
  const int m  = bi / 13;
  const int y0 = yt*5, x0 = xt*16;
  const int wave = tid >> 6, lane = tid & 63;

  {
    const size_t rowbase = ((size_t)(m*4 + cb) * 96 + y0) * 96;
    for (int k = tid; k < 36*48; k += 256) {
      const int rho = k / 48;
      const int px  = k - rho*48;
      int X = x0 + px; if (X > 95) X = 95;     // clamped feeds only x>=65 (never stored)
      *(uint4*)(&patch[(size_t)k*8]) = *(const uint4*)(&satT[(rowbase + (size_t)rho*96 + X)*8]);
    }
  }
  __syncthreads();

  const int pr = lane & 15;       // A row (x-offset) == B col
  const int q  = lane >> 4;

  floatx4 acc[5];
  #pragma unroll
  for (int r = 0; r < 5; ++r) acc[r] = (floatx4){0.f, 0.f, 0.f, 0.f};

  #pragma unroll
  for (int jbi = 0; jbi < 2; ++jbi) {
    const int jb = wave*2 + jbi;
    const int apx = pr + jb*4 + q;                         // <= 46
    const u16* bp = gP + ((size_t)cb*1024 + (size_t)(jb*4+q))*128 + (size_t)pr*8;

    uint4 Br[8];
    #pragma unroll
    for (int ii = 0; ii < 8; ++ii) Br[ii] = *(const uint4*)(bp + (size_t)ii*4096);
    uint4 Ah[8];
    #pragma unroll
    for (int s = 0; s < 6; ++s) Ah[s] = *(const uint4*)(&patch[((size_t)s*48 + apx)*8]);

    #pragma unroll
    for (int i = 0; i < 32; ++i) {
      if (i < 30)
        Ah[(i+6)&7] = *(const uint4*)(&patch[((size_t)(i+6)*48 + apx)*8]);
      const bf16x8 bf = __builtin_bit_cast(bf16x8, Br[i&7]);
      if (i < 24)
        Br[(i+8)&7] = *(const uint4*)(bp + (size_t)(i+8)*4096);
      #pragma unroll
      for (int r = 0; r < 5; ++r)
        acc[r] = __builtin_amdgcn_mfma_f32_16x16x32_bf16(
            __builtin_bit_cast(bf16x8, Ah[(i+r)&7]), bf, acc[r], 0, 0, 0);
    }
  }

  // combine hi (cols 0-7) + lo (cols 8-15): partner lane differs in bit 3
  float vals[20];
  #pragma unroll
  for (int r = 0; r < 5; ++r)
    #pragma unroll
    for (int e = 0; e < 4; ++e)
      vals[r*4+e] = acc[r][e] + __shfl_xor(acc[r][e], 8);

  // cross-wave K-sum via LDS, then wave 0 stores the cb-plane partial
  __syncthreads();
  float* red = (float*)patch;                    // 21504 B <= 27648
  #pragma unroll
  for (int u = 0; u < 20; ++u) red[((size_t)wave*64 + lane)*21 + u] = vals[u];
  __syncthreads();
  if (wave == 0 && pr < 8) {
    #pragma unroll
    for (int r = 0; r < 5; ++r) {
      #pragma unroll
      for (int e = 0; e < 4; ++e) {
        const int x = x0 + q*4 + e;
        if (x < 65) {
          float s = 0.f;
          #pragma unroll
          for (int w = 0; w < 4; ++w) s += red[((size_t)w*64 + lane)*21 + r*4 + e];
          corr_p[(size_t)cb*270400 + ((size_t)(m*8+pr)*65 + (y0+r))*65 + x] = s;
        }
      }
    }
  }
}

// ---- K3: normalize + chunk max. 320 blocks = (m,n,yc5); 13 rows each.
// Diag blocks also write v to vdiag. ----
__global__ __launch_bounds__(256) void k_vmax(
    const float* __restrict__ corr_p, const float* __restrict__ part,
    const float* __restrict__ nrmp, const float* __restrict__ gnrm,
    const int* __restrict__ tm, float* __restrict__ vdiag,
    float* __restrict__ pmax)
{
  __shared__ float red[256];
  const int bi = blockIdx.x;
  const int m = bi / 40, n = (bi / 5) & 7, yc = bi % 5;
  const int t = threadIdx.x;
  red[t] = (t < 96) ? nrmp[m*96 + t] : 0.f;
  __syncthreads();
  for (int s = 128; s > 0; s >>= 1) { if (t < s) red[t] += red[t+s]; __syncthreads(); }
  const float srn = 1.f / fmaxf(sqrtf(red[0]), 1e-12f);
  const float grn = 1.f / fmaxf(sqrtf(gnrm[n]), 1e-12f);
  const float cscale = grn * srn, pscale = srn * srn;
  const int method = tm[0];
  const float* cp = corr_p + (size_t)(m*8+n)*4225;
  const float* pp = part + (size_t)m*4225;
  const int i0 = yc*845, i1 = i0 + 845;     // 13 rows x 65
  const bool diag = (m == n);
  float bestv = -3.4e38f;
  for (int idx = i0 + t; idx < i1; idx += 256) {
    const float c = cp[idx] + cp[idx+270400] + cp[idx+540800] + cp[idx+811200];
    const float pt = pp[idx] * pscale;
    float denom = (method == 0) ? sqrtf(pt) : pt;
    denom = fmaxf(denom, 1e-12f);
    const float v = c * cscale / denom;
    if (diag) vdiag[(size_t)m*4225 + idx] = v;
    bestv = fmaxf(bestv, v);
  }
  __syncthreads();
  red[t] = bestv; __syncthreads();
  for (int s = 128; s > 0; s >>= 1) { if (t < s) red[t] = fmaxf(red[t], red[t+s]); __syncthreads(); }
  if (t == 0) pmax[bi] = red[0];
}

// ---- K4: block 8: similarity out. blocks 0-7: diag candidates + exact refine + mask. ----
__global__ __launch_bounds__(256) void k_out(
    const float* __restrict__ vdiag, const float* __restrict__ pmax,
    const float* __restrict__ grd, const float* __restrict__ sat,
    const float* __restrict__ part, const float* __restrict__ nrmp,
    const float* __restrict__ gnrm, const int* __restrict__ tm,
    const float* __restrict__ gmask, float* __restrict__ out)
{
  const int t = threadIdx.x;
  if (blockIdx.x == 8) {
    if (t < 64) {
      float v = pmax[t*5];
      #pragma unroll
      for (int k = 1; k < 5; ++k) v = fmaxf(v, pmax[t*5 + k]);
      out[t] = v;
    }
    return;
  }
  const int n = blockIdx.x;
  __shared__ float red[256];
  __shared__ int cands[64];
  __shared__ int ccnt;
  __shared__ float sbest; __shared__ int sbix;

  red[t] = (t < 96) ? nrmp[n*96 + t] : 0.f;
  __syncthreads();
  for (int s = 128; s > 0; s >>= 1) { if (t < s) red[t] += red[t+s]; __syncthreads(); }
  const float srn = 1.f / fmaxf(sqrtf(red[0]), 1e-12f);
  const float grn = 1.f / fmaxf(sqrtf(gnrm[n]), 1e-12f);
  const float cscale = grn * srn, pscale = srn * srn;
  const int method = tm[0];

  float vm = pmax[n*45];              // (n*8+n)*5
  #pragma unroll
  for (int k = 1; k < 5; ++k) vm = fmaxf(vm, pmax[n*45 + k]);
  if (t == 0) { ccnt = 0; sbest = -3.4e38f; sbix = 0x7FFFFFFF; }
  __syncthreads();
  const float thr = vm - 3e-3f;       // >> 2-term split error (~1e-5)
  const float* vd = vdiag + (size_t)n*4225;
  for (int idx = t; idx < 4225; idx += 256)
    if (vd[idx] >= thr) { const int s = atomicAdd(&ccnt, 1); if (s < 64) cands[s] = idx; }
  __syncthreads();
  int nc = ccnt; if (nc > 64) nc = 64; if (nc < 1) nc = 1;

  const int c = t >> 3, s8 = t & 7;
  for (int ci = 0; ci < nc; ++ci) {
    const int idx = cands[ci];
    const int y = idx / 65, x = idx - y*65;
    float a = 0.f;
    #pragma unroll
    for (int ii = 0; ii < 4; ++ii) {
      const int i = s8 + ii*8;
      const float* gr = grd + ((size_t)n*32 + c)*1024 + i*32;
      const float* sr = sat + (((size_t)n*32 + c)*128 + (16 + y + i))*128 + (16 + x);
      #pragma unroll
      for (int j = 0; j < 32; ++j) a += gr[j] * sr[j];
    }
    red[t] = a; __syncthreads();
    for (int st = 128; st > 0; st >>= 1) { if (t < st) red[t] += red[t+st]; __syncthreads(); }
    if (t == 0) {
      const float pt = part[(size_t)n*4225 + idx] * pscale;
      float denom = (method == 0) ? sqrtf(pt) : pt;
      denom = fmaxf(denom, 1e-12f);
      const float v = red[0] * cscale / denom;
      if (v > sbest || (v == sbest && idx < sbix)) { sbest = v; sbix = idx; }
    }
    __syncthreads();
  }
  const int bix = sbix;
  const int ph = bix / 65, pw = bix - (bix/65)*65;
  for (int p = t; p < 1024; p += 256)
    out[64 + (size_t)n*9216 + (size_t)(ph + (p>>5))*96 + (pw + (p&31))] = gmask[n*1024 + p];
}

extern "C" void kernel_launch(void* const* d_in, const int* in_sizes, int n_in,
                              void* d_out, int out_size, void* d_ws, size_t ws_size,
                              hipStream_t stream) {
  const float* grd = (const float*)d_in[0];
  const float* sat = (const float*)d_in[1];
  const int*   tm  = (const int*)d_in[2];
  float* out = (float*)d_out;
  char* ws = (char*)d_ws;

  float* corrp = (float*)(ws + OFF_CORRP);
  u16*   sTh   = (u16*)(ws + OFF_SATT);
  u16*   gP    = (u16*)(ws + OFF_GRDP);
  float* s2    = (float*)(ws + OFF_S2);
  float* part  = (float*)(ws + OFF_PART);
  float* nrmp  = (float*)(ws + OFF_NRMP);
  float* gnrm  = (float*)(ws + OFF_GNRM);
  float* gmask = (float*)(ws + OFF_MASK);
  float* vdiag = (float*)(ws + OFF_VDIAG);
  float* pmax  = (float*)(ws + OFF_PMAX);

  hipMemsetAsync(d_out, 0, (size_t)out_size * sizeof(float), stream);

  k_prep<<<776,  256, 0, stream>>>(grd, sat, sTh, gP, s2, nrmp, gnrm, gmask);
  k_conv<<<2152, 256, 0, stream>>>(sTh, gP, s2, corrp, part);
  k_vmax<<<320,  256, 0, stream>>>(corrp, part, nrmp, gnrm, tm, vdiag, pmax);
  k_out <<<9,    256, 0, stream>>>(vdiag, pmax, grd, sat, part, nrmp, gnrm, tm, gmask, out);
}

// Round 8
// 148.855 us; speedup vs baseline: 1.4643x; 1.0379x over previous
//
#include <hip/hip_runtime.h>
#include <stdint.h>

typedef unsigned short u16;
typedef unsigned int u32;
typedef unsigned long long u64;
typedef __bf16 bf16x8 __attribute__((ext_vector_type(8)));
typedef float floatx4 __attribute__((ext_vector_type(4)));

#define DEVI static __device__ __forceinline__

DEVI u16 f2bf(float f) {
  uint32_t u = __builtin_bit_cast(uint32_t, f);
  u += 0x7FFFu + ((u >> 16) & 1u);
  return (u16)(u >> 16);
}
DEVI float bf2f(u16 b) { return __builtin_bit_cast(float, (uint32_t)b << 16); }

// order-preserving float<->uint encoding
DEVI u32 encf(float f) {
  u32 u = __builtin_bit_cast(u32, f);
  return (u >> 31) ? ~u : (u | 0x80000000u);
}
DEVI float decf(u32 e) {
  u32 u = (e >> 31) ? (e & 0x7FFFFFFFu) : ~e;
  return __builtin_bit_cast(float, u);
}

// ---- workspace layout (bytes) ----
static constexpr size_t OFF_CORRP = 0;                                   // f32 [cb4][m][n][65][65]
static constexpr size_t OFF_SATT  = OFF_CORRP + (size_t)4*270400*4;      // bf16 [m][cb][y][x][c8]
static constexpr size_t OFF_GRDP  = OFF_SATT + (size_t)8*4*96*96*8*2;    // bf16 [cb][i*32+j][col16][c8]
static constexpr size_t OFF_S2    = OFF_GRDP + (size_t)4*1024*16*8*2;    // f32 [8][96][96]
static constexpr size_t OFF_PART  = OFF_S2   + (size_t)73728*4;          // f32 [8][65][65]
static constexpr size_t OFF_NRMP  = OFF_PART + (size_t)33800*4;          // f32 sat nrm partials [8][96]
static constexpr size_t OFF_GNRM  = OFF_NRMP + 768*4;                    // f32 grd nrm2 [8]
static constexpr size_t OFF_MASK  = OFF_GNRM + 32;                       // f32 [8][1024]
static constexpr size_t OFF_PMAX  = OFF_MASK + (size_t)8192*4;           // u32 enc chunk max [320]
static constexpr size_t OFF_CNT   = OFF_PMAX + 320*4;                    // u32 grpcnt[64] + candcnt[8]
static constexpr size_t OFF_CAND  = OFF_CNT  + 512;                      // u64 cand[8][128]

// ---- K1: blocks 0..767: one sat row -> bf16 channels-last + s2 + norm partial.
//          blocks 768..775: grd pack. block 776: zero counters.
__global__ __launch_bounds__(256) void k_prep(
    const float* __restrict__ grd, const float* __restrict__ sat,
    u16* __restrict__ sTh, u16* __restrict__ gP,
    float* __restrict__ s2, float* __restrict__ nrmp,
    float* __restrict__ gnrm, float* __restrict__ gmask,
    u32* __restrict__ cnts) {
  __shared__ float L[32*100];
  __shared__ float red[256];
  const int t = threadIdx.x;
  if (blockIdx.x < 768) {
    const int m = blockIdx.x / 96, y = blockIdx.x - (blockIdx.x / 96) * 96;
    #pragma unroll
    for (int k = 0; k < 3; ++k) {
      const int idx = k*256 + t;
      const int c = idx / 24, xq = idx - c*24;
      const float4 v = *(const float4*)(sat + (((size_t)m*32 + c)*128 + (16+y))*128 + 16 + xq*4);
      *(float4*)(&L[c*100 + xq*4]) = v;
    }
    __syncthreads();
    float ss = 0.f;
    if (t < 96) {
      #pragma unroll
      for (int c = 0; c < 32; ++c) { const float v = L[c*100 + t]; ss += v*v; }
      s2[(size_t)m*9216 + y*96 + t] = ss;
    }
    red[t] = ss; __syncthreads();
    for (int s = 128; s > 0; s >>= 1) { if (t < s) red[t] += red[t+s]; __syncthreads(); }
    if (t == 0) nrmp[m*96 + y] = red[0];
    for (int idx = t; idx < 384; idx += 256) {
      const int cb = idx / 96, x = idx - cb*96;
      union { u16 us[8]; uint4 v4; } P;
      #pragma unroll
      for (int e = 0; e < 8; ++e) P.us[e] = f2bf(L[(cb*8+e)*100 + x]);
      *(uint4*)(&sTh[(((size_t)m*4+cb)*9216 + (size_t)y*96 + x)*8]) = P.v4;
    }
  } else if (blockIdx.x == 776) {
    if (t < 72) cnts[t] = 0u;      // grpcnt[64] + candcnt[8]
  } else {
    const int n = blockIdx.x - 768;
    float nn = 0.f, scs[4];
    #pragma unroll
    for (int it = 0; it < 4; ++it) {
      const int pidx = it*256 + t;
      float vals[32]; float sc = 0.f;
      #pragma unroll
      for (int c = 0; c < 32; ++c) {
        const float v = grd[((size_t)n*32 + c)*1024 + pidx];
        vals[c] = v; sc += v; nn += v*v;
      }
      scs[it] = sc;
      #pragma unroll
      for (int cb = 0; cb < 4; ++cb) {
        union { u16 us[8]; uint4 v4; } ph, pl;
        #pragma unroll
        for (int e = 0; e < 8; ++e) {
          const float v = vals[cb*8+e];
          const u16 h = f2bf(v); ph.us[e] = h; pl.us[e] = f2bf(v - bf2f(h));
        }
        const size_t o = ((size_t)cb*1024 + pidx)*128;
        *(uint4*)(&gP[o + (size_t)n*8])     = ph.v4;
        *(uint4*)(&gP[o + (size_t)(n+8)*8]) = pl.v4;
      }
    }
    red[t] = nn; __syncthreads();
    for (int s = 128; s > 0; s >>= 1) { if (t < s) red[t] += red[t+s]; __syncthreads(); }
    const float gn = fmaxf(sqrtf(red[0]), 1e-12f);
    if (t == 0) gnrm[n] = red[0];
    const float thr = 1e-6f * gn;
    #pragma unroll
    for (int it = 0; it < 4; ++it)
      gmask[n*1024 + it*256 + t] = (fabsf(scs[it]) > thr) ? 1.f : 0.f;
  }
}

// ---- K2: blocks 0..1663: main conv (m8,yt13,xt4,cb4), x-cols 0..63 (zero waste).
//          blocks 1664..1823: edge conv x=64 (m8,yt5,cb4), M = 16 y-rows (13 used).
//          blocks 1824..1895: 32x32 window-sum of s2 -> part.
__global__ __launch_bounds__(256, 4) void k_conv(
    const u16* __restrict__ satT, const u16* __restrict__ gP,
    const float* __restrict__ s2, float* __restrict__ corr_p,
    float* __restrict__ part)
{
  __shared__ __align__(16) u16 patch[36*48*8];   // 27648 B

  const int bi = blockIdx.x;
  const int tid = threadIdx.x;

  if (bi >= 1824) {            // ---- part blocks ----
    float* S  = (float*)patch;          // [<=40][96]
    float* HS = S + 40*96;              // [<=39][65]
    const int pb = bi - 1824;
    const int pm = pb / 9, ysl = (pb - pm*9)*8;
    const int nrows = (65 - ysl) < 8 ? (65 - ysl) : 8;
    const int scnt  = (96 - ysl) < 40 ? (96 - ysl) : 40;
    for (int idx = tid; idx < scnt*96; idx += 256)
      S[idx] = s2[(size_t)pm*9216 + (size_t)ysl*96 + idx];
    __syncthreads();
    const int hrows = nrows + 31;
    for (int idx = tid; idx < hrows*65; idx += 256) {
      const int r = idx / 65, xo = idx - r*65;
      const float* p = &S[r*96 + xo];
      float s = 0.f;
      #pragma unroll
      for (int j = 0; j < 32; ++j) s += p[j];
      HS[idx] = s;
    }
    __syncthreads();
    for (int idx = tid; idx < nrows*65; idx += 256) {
      const int r = idx / 65, xo = idx - r*65;
      float s = 0.f;
      #pragma unroll
      for (int i = 0; i < 32; ++i) s += HS[(r+i)*65 + xo];
      part[(size_t)pm*4225 + (size_t)(ysl+r)*65 + xo] = s;
    }
    return;
  }

  const int wave = tid >> 6, lane = tid & 63;
  const int pr = lane & 15, q = lane >> 4;

  if (bi >= 1664) {            // ---- edge blocks: x = 64 column ----
    const int e = bi - 1664;
    const int cb = e & 3;
    const int yt = (e >> 2) % 5;
    const int m  = e / 20;
    const int ybase = yt * 13;
    // stage 44 rows x 32 px (x 64..95), LDS [rho][px][c8]
    const size_t rowbase = ((size_t)(m*4 + cb) * 96 + ybase) * 96;
    for (int k = tid; k < 44*32; k += 256) {
      const int rho = k >> 5, px = k & 31;
      *(uint4*)(&patch[(size_t)k*8]) =
          *(const uint4*)(&satT[(rowbase + (size_t)rho*96 + 64 + px)*8]);
    }
    __syncthreads();
    const int prc = pr < 13 ? pr : 12;   // rows 13-15 duplicate row 12 (D rows discarded)
    floatx4 acc = (floatx4){0.f, 0.f, 0.f, 0.f};
    #pragma unroll
    for (int jbi = 0; jbi < 2; ++jbi) {
      const int jb = wave*2 + jbi;
      const int px_e = jb*4 + q;                          // 0..31
      const u16* bp = gP + ((size_t)cb*1024 + (size_t)(jb*4+q))*128 + (size_t)pr*8;
      uint4 Br[8];
      #pragma unroll
      for (int ii = 0; ii < 8; ++ii) Br[ii] = *(const uint4*)(bp + (size_t)ii*4096);
      uint4 Ah[8];
      #pragma unroll
      for (int s = 0; s < 6; ++s)
        Ah[s] = *(const uint4*)(&patch[((size_t)(prc + s)*32 + px_e)*8]);
      #pragma unroll
      for (int i = 0; i < 32; ++i) {
        if (i < 26)      // row prc+i+6 <= 43; consume slot i&7 (init 0-5, prefetch i-6)
          Ah[(i+6)&7] = *(const uint4*)(&patch[((size_t)(prc + i + 6)*32 + px_e)*8]);
        const bf16x8 bf = __builtin_bit_cast(bf16x8, Br[i&7]);
        if (i < 24)
          Br[(i+8)&7] = *(const uint4*)(bp + (size_t)(i+8)*4096);
        acc = __builtin_amdgcn_mfma_f32_16x16x32_bf16(
            __builtin_bit_cast(bf16x8, Ah[i&7]), bf, acc, 0, 0, 0);
      }
    }
    float v4[4];
    #pragma unroll
    for (int k = 0; k < 4; ++k) v4[k] = acc[k] + __shfl_xor(acc[k], 8);
    __syncthreads();
    float* red = (float*)patch;
    #pragma unroll
    for (int k = 0; k < 4; ++k) red[((size_t)wave*64 + lane)*5 + k] = v4[k];
    __syncthreads();
    if (wave == 0 && pr < 8) {
      #pragma unroll
      for (int k = 0; k < 4; ++k) {
        const int yoff = q*4 + k;
        if (yoff < 13) {
          float s = 0.f;
          #pragma unroll
          for (int w = 0; w < 4; ++w) s += red[((size_t)w*64 + lane)*5 + k];
          corr_p[(size_t)cb*270400 + ((size_t)(m*8+pr)*65 + (ybase+yoff))*65 + 64] = s;
        }
      }
    }
    return;
  }

  // ---- main conv blocks ----
  int b = bi;
  const int cb = b & 3; b >>= 2;
  const int xt = b % 4; b /= 4;
  const int yt = b % 13;
  const int m  = b / 13;
  const int y0 = yt*5, x0 = xt*16;

  {
    const size_t rowbase = ((size_t)(m*4 + cb) * 96 + y0) * 96;
    for (int k = tid; k < 36*48; k += 256) {
      const int rho = k / 48;
      const int px  = k - rho*48;
      *(uint4*)(&patch[(size_t)k*8]) =
          *(const uint4*)(&satT[(rowbase + (size_t)rho*96 + x0 + px)*8]);   // x0+px <= 95
    }
  }
  __syncthreads();

  floatx4 acc[5];
  #pragma unroll
  for (int r = 0; r < 5; ++r) acc[r] = (floatx4){0.f, 0.f, 0.f, 0.f};

  #pragma unroll
  for (int jbi = 0; jbi < 2; ++jbi) {
    const int jb = wave*2 + jbi;
    const int apx = pr + jb*4 + q;                         // <= 46
    const u16* bp = gP + ((size_t)cb*1024 + (size_t)(jb*4+q))*128 + (size_t)pr*8;

    uint4 Br[8];
    #pragma unroll
    for (int ii = 0; ii < 8; ++ii) Br[ii] = *(const uint4*)(bp + (size_t)ii*4096);
    uint4 Ah[8];
    #pragma unroll
    for (int s = 0; s < 6; ++s) Ah[s] = *(const uint4*)(&patch[((size_t)s*48 + apx)*8]);

    #pragma unroll
    for (int i = 0; i < 32; ++i) {
      if (i < 30)
        Ah[(i+6)&7] = *(const uint4*)(&patch[((size_t)(i+6)*48 + apx)*8]);
      const bf16x8 bf = __builtin_bit_cast(bf16x8, Br[i&7]);
      if (i < 24)
        Br[(i+8)&7] = *(const uint4*)(bp + (size_t)(i+8)*4096);
      #pragma unroll
      for (int r = 0; r < 5; ++r)
        acc[r] = __builtin_amdgcn_mfma_f32_16x16x32_bf16(
            __builtin_bit_cast(bf16x8, Ah[(i+r)&7]), bf, acc[r], 0, 0, 0);
    }
  }

  float vals[20];
  #pragma unroll
  for (int r = 0; r < 5; ++r)
    #pragma unroll
    for (int k = 0; k < 4; ++k)
      vals[r*4+k] = acc[r][k] + __shfl_xor(acc[r][k], 8);

  __syncthreads();
  float* red = (float*)patch;
  #pragma unroll
  for (int u = 0; u < 20; ++u) red[((size_t)wave*64 + lane)*21 + u] = vals[u];
  __syncthreads();
  if (wave == 0 && pr < 8) {
    #pragma unroll
    for (int r = 0; r < 5; ++r) {
      #pragma unroll
      for (int k = 0; k < 4; ++k) {
        const int x = x0 + q*4 + k;    // <= 63, always valid
        float s = 0.f;
        #pragma unroll
        for (int w = 0; w < 4; ++w) s += red[((size_t)w*64 + lane)*21 + r*4 + k];
        corr_p[(size_t)cb*270400 + ((size_t)(m*8+pr)*65 + (y0+r))*65 + x] = s;
      }
    }
  }
}

// ---- K3: fused normalize/max/refine. 320 blocks = (m,n,yc5); per-(m,n) group
// last-block pattern with device-scope atomics ONLY for cross-block data. ----
__global__ __launch_bounds__(256) void k_post(
    const float* __restrict__ corr_p, const float* __restrict__ part,
    const float* __restrict__ nrmp, const float* __restrict__ gnrm,
    const int* __restrict__ tm, const float* __restrict__ grd,
    const float* __restrict__ sat, const float* __restrict__ gmask,
    u32* __restrict__ pmaxE, u32* __restrict__ grpcnt,
    u32* __restrict__ candcnt, u64* __restrict__ cand,
    float* __restrict__ out)
{
  __shared__ float red[256];
  __shared__ float s_bcast;
  __shared__ int s_last;
  __shared__ int fidx[128];
  __shared__ u32 fcnt;

  const int bi = blockIdx.x;
  const int m = bi / 40, n = (bi / 5) & 7, yc = bi % 5, g = m*8 + n;
  const int t = threadIdx.x;
  const bool diag = (m == n);

  red[t] = (t < 96) ? nrmp[m*96 + t] : 0.f;
  __syncthreads();
  for (int s = 128; s > 0; s >>= 1) { if (t < s) red[t] += red[t+s]; __syncthreads(); }
  const float srn = 1.f / fmaxf(sqrtf(red[0]), 1e-12f);
  const float grn = 1.f / fmaxf(sqrtf(gnrm[n]), 1e-12f);
  const float cscale = grn * srn, pscale = srn * srn;
  const int method = tm[0];

  const float* cp = corr_p + (size_t)g*4225;
  const float* pp = part + (size_t)m*4225;
  const int i0 = yc*845, i1 = i0 + 845;
  float vv[4];
  float bestv = -3.4e38f;
  #pragma unroll
  for (int k = 0; k < 4; ++k) {
    const int idx = i0 + k*256 + t;
    float v = -3.4e38f;
    if (idx < i1) {
      const float c = cp[idx] + cp[idx+270400] + cp[idx+540800] + cp[idx+811200];
      const float pt = pp[idx] * pscale;
      float denom = (method == 0) ? sqrtf(pt) : pt;
      denom = fmaxf(denom, 1e-12f);
      v = c * cscale / denom;
    }
    vv[k] = v;
    bestv = fmaxf(bestv, v);
  }
  __syncthreads();
  red[t] = bestv; __syncthreads();
  for (int s = 128; s > 0; s >>= 1) { if (t < s) red[t] = fmaxf(red[t], red[t+s]); __syncthreads(); }
  if (t == 0) { s_bcast = red[0]; atomicExch(&pmaxE[bi], encf(red[0])); }
  __syncthreads();
  if (diag) {                         // local candidate collect (superset of global)
    const float lthr = s_bcast - 3e-3f;
    #pragma unroll
    for (int k = 0; k < 4; ++k) {
      const int idx = i0 + k*256 + t;
      if (idx < i1 && vv[k] >= lthr) {
        const u32 s = atomicAdd(&candcnt[n], 1u);
        if (s < 128)
          atomicExch(&cand[n*128 + s],
                     ((u64)__builtin_bit_cast(u32, vv[k]) << 32) | (u32)idx);
      }
    }
  }
  __syncthreads();                    // drains all memory ops before counter bump
  if (t == 0) s_last = (atomicAdd(&grpcnt[g], 1u) == 4u) ? 1 : 0;
  __syncthreads();
  if (!s_last) return;

  // ---- group-last: similarity ----
  if (t == 0) {
    float gm = -3.4e38f;
    #pragma unroll
    for (int k = 0; k < 5; ++k) gm = fmaxf(gm, decf(atomicOr(&pmaxE[g*5 + k], 0u)));
    out[g] = gm;
    s_bcast = gm;
  }
  __syncthreads();
  if (!diag) return;

  // ---- diag-last: filter candidates by global max, exact refine, mask ----
  const float gmax = s_bcast;
  const float thr = gmax - 3e-3f;     // >> 2-term split error (~1e-5)
  if (t == 0) fcnt = 0u;
  __syncthreads();
  u32 nc = atomicAdd(&candcnt[n], 0u); if (nc > 128) nc = 128;
  if (t < (int)nc) {
    const u64 pk = atomicAdd(&cand[n*128 + t], 0ULL);
    const float vf = __builtin_bit_cast(float, (u32)(pk >> 32));
    const int idx = (int)(u32)pk;
    if (vf >= thr) { const u32 s = atomicAdd(&fcnt, 1u); fidx[s] = idx; }
  }
  __syncthreads();
  if (t == 0 && fcnt == 0u) { fidx[0] = 0; fcnt = 1u; }   // unreachable safety
  __syncthreads();
  const int nf = (int)fcnt;

  __shared__ float sbest; __shared__ int sbix;
  if (t == 0) { sbest = -3.4e38f; sbix = 0x7FFFFFFF; }
  __syncthreads();
  const int c = t >> 3, s8 = t & 7;
  for (int ci = 0; ci < nf; ++ci) {
    const int idx = fidx[ci];
    const int y = idx / 65, x = idx - y*65;
    float a = 0.f;
    #pragma unroll
    for (int ii = 0; ii < 4; ++ii) {
      const int i = s8 + ii*8;
      const float* gr = grd + ((size_t)n*32 + c)*1024 + i*32;
      const float* sr = sat + (((size_t)n*32 + c)*128 + (16 + y + i))*128 + (16 + x);
      #pragma unroll
      for (int j = 0; j < 32; ++j) a += gr[j] * sr[j];
    }
    red[t] = a; __syncthreads();
    for (int st = 128; st > 0; st >>= 1) { if (t < st) red[t] += red[t+st]; __syncthreads(); }
    if (t == 0) {
      const float pt = part[(size_t)n*4225 + idx] * pscale;
      float denom = (method == 0) ? sqrtf(pt) : pt;
      denom = fmaxf(denom, 1e-12f);
      const float v = red[0] * cscale / denom;
      if (v > sbest || (v == sbest && idx < sbix)) { sbest = v; sbix = idx; }
    }
    __syncthreads();
  }
  const int bix = sbix;
  const int ph = bix / 65, pw = bix - (bix/65)*65;
  // full mask plane: zeros + scattered 32x32 grd_mask patch (no memset needed)
  for (int p = t; p < 9216; p += 256) {
    const int yy = p / 96, xx = p - yy*96;
    float val = 0.f;
    if (yy >= ph && yy < ph+32 && xx >= pw && xx < pw+32)
      val = gmask[n*1024 + (yy-ph)*32 + (xx-pw)];
    out[64 + (size_t)n*9216 + p] = val;
  }
}

extern "C" void kernel_launch(void* const* d_in, const int* in_sizes, int n_in,
                              void* d_out, int out_size, void* d_ws, size_t ws_size,
                              hipStream_t stream) {
  const float* grd = (const float*)d_in[0];
  const float* sat = (const float*)d_in[1];
  const int*   tm  = (const int*)d_in[2];
  float* out = (float*)d_out;
  char* ws = (char*)d_ws;

  float* corrp = (float*)(ws + OFF_CORRP);
  u16*   sTh   = (u16*)(ws + OFF_SATT);
  u16*   gP    = (u16*)(ws + OFF_GRDP);
  float* s2    = (float*)(ws + OFF_S2);
  float* part  = (float*)(ws + OFF_PART);
  float* nrmp  = (float*)(ws + OFF_NRMP);
  float* gnrm  = (float*)(ws + OFF_GNRM);
  float* gmask = (float*)(ws + OFF_MASK);
  u32*   pmaxE = (u32*)(ws + OFF_PMAX);
  u32*   cnts  = (u32*)(ws + OFF_CNT);       // grpcnt[64] then candcnt[8]
  u64*   cand  = (u64*)(ws + OFF_CAND);

  k_prep<<<777,  256, 0, stream>>>(grd, sat, sTh, gP, s2, nrmp, gnrm, gmask, cnts);
  k_conv<<<1896, 256, 0, stream>>>(sTh, gP, s2, corrp, part);
  k_post<<<320,  256, 0, stream>>>(corrp, part, nrmp, gnrm, tm, grd, sat, gmask,
                                   pmaxE, cnts, cnts + 64, cand, out);
}

// Round 9
// 147.589 us; speedup vs baseline: 1.4769x; 1.0086x over previous
//
#include <hip/hip_runtime.h>
#include <stdint.h>

typedef unsigned short u16;
typedef unsigned int u32;
typedef unsigned long long u64;
typedef __bf16 bf16x8 __attribute__((ext_vector_type(8)));
typedef float floatx4 __attribute__((ext_vector_type(4)));

#define DEVI static __device__ __forceinline__

DEVI u16 f2bf(float f) {
  uint32_t u = __builtin_bit_cast(uint32_t, f);
  u += 0x7FFFu + ((u >> 16) & 1u);
  return (u16)(u >> 16);
}
DEVI float bf2f(u16 b) { return __builtin_bit_cast(float, (uint32_t)b << 16); }

// order-preserving float<->uint encoding
DEVI u32 encf(float f) {
  u32 u = __builtin_bit_cast(u32, f);
  return (u >> 31) ? ~u : (u | 0x80000000u);
}
DEVI float decf(u32 e) {
  u32 u = (e >> 31) ? (e & 0x7FFFFFFFu) : ~e;
  return __builtin_bit_cast(float, u);
}

// async global->LDS 16B (lds dest = wave-uniform base + lane*16: our k=wavebase+lane layout matches)
DEVI void cp16(const u16* g, u16* l) {
#if __has_builtin(__builtin_amdgcn_global_load_lds)
  __builtin_amdgcn_global_load_lds(
      (const __attribute__((address_space(1))) uint32_t*)g,
      (__attribute__((address_space(3))) uint32_t*)l, 16, 0, 0);
#else
  *(uint4*)l = *(const uint4*)g;
#endif
}

// ---- workspace layout (bytes) ----
static constexpr size_t OFF_CORRP = 0;                                   // f32 [cb4][m][n][65][65]
static constexpr size_t OFF_SATT  = OFF_CORRP + (size_t)4*270400*4;      // bf16 [m][cb][y][x][c8]
static constexpr size_t OFF_GRDP  = OFF_SATT + (size_t)8*4*96*96*8*2;    // bf16 [cb][i*32+j][col16][c8]
static constexpr size_t OFF_S2    = OFF_GRDP + (size_t)4*1024*16*8*2;    // f32 [8][96][96]
static constexpr size_t OFF_PART  = OFF_S2   + (size_t)73728*4;          // f32 [8][65][65]
static constexpr size_t OFF_NRMP  = OFF_PART + (size_t)33800*4;          // f32 sat nrm partials [8][96]
static constexpr size_t OFF_GNRM  = OFF_NRMP + 768*4;                    // f32 grd nrm2 [8]
static constexpr size_t OFF_MASK  = OFF_GNRM + 32;                       // f32 [8][1024]
static constexpr size_t OFF_PMAX  = OFF_MASK + (size_t)8192*4;           // u32 enc chunk max [320]
static constexpr size_t OFF_CNT   = OFF_PMAX + 320*4;                    // u32 grpcnt[64] + candcnt[8]
static constexpr size_t OFF_CAND  = OFF_CNT  + 512;                      // u64 cand[8][128]

// ---- K1: blocks 0..767: one sat row -> bf16 channels-last + s2 + norm partial.
//          blocks 768..775: grd pack. block 776: zero counters. (unchanged from r8)
__global__ __launch_bounds__(256) void k_prep(
    const float* __restrict__ grd, const float* __restrict__ sat,
    u16* __restrict__ sTh, u16* __restrict__ gP,
    float* __restrict__ s2, float* __restrict__ nrmp,
    float* __restrict__ gnrm, float* __restrict__ gmask,
    u32* __restrict__ cnts) {
  __shared__ float L[32*100];
  __shared__ float red[256];
  const int t = threadIdx.x;
  if (blockIdx.x < 768) {
    const int m = blockIdx.x / 96, y = blockIdx.x - (blockIdx.x / 96) * 96;
    #pragma unroll
    for (int k = 0; k < 3; ++k) {
      const int idx = k*256 + t;
      const int c = idx / 24, xq = idx - c*24;
      const float4 v = *(const float4*)(sat + (((size_t)m*32 + c)*128 + (16+y))*128 + 16 + xq*4);
      *(float4*)(&L[c*100 + xq*4]) = v;
    }
    __syncthreads();
    float ss = 0.f;
    if (t < 96) {
      #pragma unroll
      for (int c = 0; c < 32; ++c) { const float v = L[c*100 + t]; ss += v*v; }
      s2[(size_t)m*9216 + y*96 + t] = ss;
    }
    red[t] = ss; __syncthreads();
    for (int s = 128; s > 0; s >>= 1) { if (t < s) red[t] += red[t+s]; __syncthreads(); }
    if (t == 0) nrmp[m*96 + y] = red[0];
    for (int idx = t; idx < 384; idx += 256) {
      const int cb = idx / 96, x = idx - cb*96;
      union { u16 us[8]; uint4 v4; } P;
      #pragma unroll
      for (int e = 0; e < 8; ++e) P.us[e] = f2bf(L[(cb*8+e)*100 + x]);
      *(uint4*)(&sTh[(((size_t)m*4+cb)*9216 + (size_t)y*96 + x)*8]) = P.v4;
    }
  } else if (blockIdx.x == 776) {
    if (t < 72) cnts[t] = 0u;
  } else {
    const int n = blockIdx.x - 768;
    float nn = 0.f, scs[4];
    #pragma unroll
    for (int it = 0; it < 4; ++it) {
      const int pidx = it*256 + t;
      float vals[32]; float sc = 0.f;
      #pragma unroll
      for (int c = 0; c < 32; ++c) {
        const float v = grd[((size_t)n*32 + c)*1024 + pidx];
        vals[c] = v; sc += v; nn += v*v;
      }
      scs[it] = sc;
      #pragma unroll
      for (int cb = 0; cb < 4; ++cb) {
        union { u16 us[8]; uint4 v4; } ph, pl;
        #pragma unroll
        for (int e = 0; e < 8; ++e) {
          const float v = vals[cb*8+e];
          const u16 h = f2bf(v); ph.us[e] = h; pl.us[e] = f2bf(v - bf2f(h));
        }
        const size_t o = ((size_t)cb*1024 + pidx)*128;
        *(uint4*)(&gP[o + (size_t)n*8])     = ph.v4;
        *(uint4*)(&gP[o + (size_t)(n+8)*8]) = pl.v4;
      }
    }
    red[t] = nn; __syncthreads();
    for (int s = 128; s > 0; s >>= 1) { if (t < s) red[t] += red[t+s]; __syncthreads(); }
    const float gn = fmaxf(sqrtf(red[0]), 1e-12f);
    if (t == 0) gnrm[n] = red[0];
    const float thr = 1e-6f * gn;
    #pragma unroll
    for (int it = 0; it < 4; ++it)
      gmask[n*1024 + it*256 + t] = (fabsf(scs[it]) > thr) ? 1.f : 0.f;
  }
}

// ---- K2: blocks 0..895: main conv (m8,yt7,xt4,cb4). yt<6: 10-row tile; yt=6: 5-row
//          tile (rows 60..64, proven r8 body). blocks 896..1055: edge x=64.
//          blocks 1056..1127: window-sum of s2 -> part.
__global__ __launch_bounds__(256, 3) void k_conv(
    const u16* __restrict__ satT, const u16* __restrict__ gP,
    const float* __restrict__ s2, float* __restrict__ corr_p,
    float* __restrict__ part)
{
  __shared__ __align__(16) u16 patch[41*48*8];   // 31488 B

  const int bi = blockIdx.x;
  const int tid = threadIdx.x;

  if (bi >= 1056) {            // ---- part blocks ----
    float* S  = (float*)patch;          // [<=40][96]
    float* HS = S + 40*96;              // [<=39][65]  (25500 B <= 31488)
    const int pb = bi - 1056;
    const int pm = pb / 9, ysl = (pb - pm*9)*8;
    const int nrows = (65 - ysl) < 8 ? (65 - ysl) : 8;
    const int scnt  = (96 - ysl) < 40 ? (96 - ysl) : 40;
    for (int idx = tid; idx < scnt*96; idx += 256)
      S[idx] = s2[(size_t)pm*9216 + (size_t)ysl*96 + idx];
    __syncthreads();
    const int hrows = nrows + 31;
    for (int idx = tid; idx < hrows*65; idx += 256) {
      const int r = idx / 65, xo = idx - r*65;
      const float* p = &S[r*96 + xo];
      float s = 0.f;
      #pragma unroll
      for (int j = 0; j < 32; ++j) s += p[j];
      HS[idx] = s;
    }
    __syncthreads();
    for (int idx = tid; idx < nrows*65; idx += 256) {
      const int r = idx / 65, xo = idx - r*65;
      float s = 0.f;
      #pragma unroll
      for (int i = 0; i < 32; ++i) s += HS[(r+i)*65 + xo];
      part[(size_t)pm*4225 + (size_t)(ysl+r)*65 + xo] = s;
    }
    return;
  }

  const int wave = tid >> 6, lane = tid & 63;
  const int pr = lane & 15, q = lane >> 4;

  if (bi >= 896) {             // ---- edge blocks: x = 64 column (r8-proven) ----
    const int e = bi - 896;
    const int cb = e & 3;
    const int yt = (e >> 2) % 5;
    const int m  = e / 20;
    const int ybase = yt * 13;
    const size_t rowbase = ((size_t)(m*4 + cb) * 96 + ybase) * 96;
    for (int k = tid; k < 44*32; k += 256) {
      const int rho = k >> 5, px = k & 31;
      cp16(&satT[(rowbase + (size_t)rho*96 + 64 + px)*8], &patch[(size_t)k*8]);
    }
    asm volatile("s_waitcnt vmcnt(0)" ::: "memory");
    __syncthreads();
    const int prc = pr < 13 ? pr : 12;   // rows 13-15 duplicate row 12 (D rows discarded)
    floatx4 acc = (floatx4){0.f, 0.f, 0.f, 0.f};
    #pragma unroll
    for (int jbi = 0; jbi < 2; ++jbi) {
      const int jb = wave*2 + jbi;
      const int px_e = jb*4 + q;
      const u16* bp = gP + ((size_t)cb*1024 + (size_t)(jb*4+q))*128 + (size_t)pr*8;
      uint4 Br[8];
      #pragma unroll
      for (int ii = 0; ii < 8; ++ii) Br[ii] = *(const uint4*)(bp + (size_t)ii*4096);
      uint4 Ah[8];
      #pragma unroll
      for (int s = 0; s < 6; ++s)
        Ah[s] = *(const uint4*)(&patch[((size_t)(prc + s)*32 + px_e)*8]);
      #pragma unroll
      for (int i = 0; i < 32; ++i) {
        if (i < 26)
          Ah[(i+6)&7] = *(const uint4*)(&patch[((size_t)(prc + i + 6)*32 + px_e)*8]);
        const bf16x8 bf = __builtin_bit_cast(bf16x8, Br[i&7]);
        if (i < 24)
          Br[(i+8)&7] = *(const uint4*)(bp + (size_t)(i+8)*4096);
        acc = __builtin_amdgcn_mfma_f32_16x16x32_bf16(
            __builtin_bit_cast(bf16x8, Ah[i&7]), bf, acc, 0, 0, 0);
      }
    }
    float v4[4];
    #pragma unroll
    for (int k = 0; k < 4; ++k) v4[k] = acc[k] + __shfl_xor(acc[k], 8);
    __syncthreads();
    float* red = (float*)patch;
    #pragma unroll
    for (int k = 0; k < 4; ++k) red[((size_t)wave*64 + lane)*5 + k] = v4[k];
    __syncthreads();
    if (wave == 0 && pr < 8) {
      #pragma unroll
      for (int k = 0; k < 4; ++k) {
        const int yoff = q*4 + k;
        if (yoff < 13) {
          float s = 0.f;
          #pragma unroll
          for (int w = 0; w < 4; ++w) s += red[((size_t)w*64 + lane)*5 + k];
          corr_p[(size_t)cb*270400 + ((size_t)(m*8+pr)*65 + (ybase+yoff))*65 + 64] = s;
        }
      }
    }
    return;
  }

  // ---- main conv blocks ----
  int b = bi;
  const int cb = b & 3; b >>= 2;
  const int xt = b & 3; b >>= 2;
  const int yt = b % 7;
  const int m  = b / 7;
  const int x0 = xt*16;

  if (yt < 6) {
    // ======== 10-row tile, rows y0..y0+9, patch 41 rows ========
    const int y0 = yt*10;
    const size_t rowbase = ((size_t)(m*4 + cb) * 96 + y0) * 96;
    for (int k = tid; k < 41*48; k += 256) {
      const int rho = k / 48, px = k - (k/48)*48;
      cp16(&satT[(rowbase + (size_t)rho*96 + x0 + px)*8], &patch[(size_t)k*8]);
    }
    asm volatile("s_waitcnt vmcnt(0)" ::: "memory");
    __syncthreads();

    floatx4 acc[10];
    #pragma unroll
    for (int r = 0; r < 10; ++r) acc[r] = (floatx4){0.f, 0.f, 0.f, 0.f};

    #pragma unroll
    for (int jbi = 0; jbi < 2; ++jbi) {
      const int jb = wave*2 + jbi;
      const int apx = pr + jb*4 + q;                       // <= 46
      const u16* bp = gP + ((size_t)cb*1024 + (size_t)(jb*4+q))*128 + (size_t)pr*8;

      uint4 Br[8];
      #pragma unroll
      for (int ii = 0; ii < 8; ++ii) Br[ii] = *(const uint4*)(bp + (size_t)ii*4096);
      // Ah ring depth 12: init rows 0..11; at iter i prefetch row i+12 into slot
      // (i+12)%12 == i%12 AFTER the chain (row-i read precedes in source: WAR-safe).
      // Coverage: rows 12..40 prefetched at i=0..28; max row used = 31+9 = 40.
      uint4 Ah[12];
      #pragma unroll
      for (int s = 0; s < 12; ++s) Ah[s] = *(const uint4*)(&patch[((size_t)s*48 + apx)*8]);

      #pragma unroll
      for (int i = 0; i < 32; ++i) {
        const bf16x8 bf = __builtin_bit_cast(bf16x8, Br[i&7]);
        if (i < 24)
          Br[(i+8)&7] = *(const uint4*)(bp + (size_t)(i+8)*4096);
        #pragma unroll
        for (int r = 0; r < 10; ++r)
          acc[r] = __builtin_amdgcn_mfma_f32_16x16x32_bf16(
              __builtin_bit_cast(bf16x8, Ah[(i+r)%12]), bf, acc[r], 0, 0, 0);
        if (i < 29)
          Ah[(i+12)%12] = *(const uint4*)(&patch[((size_t)(i+12)*48 + apx)*8]);
      }
    }

    float vals[40];
    #pragma unroll
    for (int r = 0; r < 10; ++r)
      #pragma unroll
      for (int k = 0; k < 4; ++k)
        vals[r*4+k] = acc[r][k] + __shfl_xor(acc[r][k], 8);

    float* red = (float*)patch;
    #pragma unroll
    for (int half = 0; half < 2; ++half) {
      __syncthreads();
      #pragma unroll
      for (int u = 0; u < 20; ++u) red[((size_t)wave*64 + lane)*21 + u] = vals[half*20 + u];
      __syncthreads();
      if (wave == 0 && pr < 8) {
        #pragma unroll
        for (int r = 0; r < 5; ++r) {
          #pragma unroll
          for (int k = 0; k < 4; ++k) {
            const int x = x0 + q*4 + k;    // <= 63
            float s = 0.f;
            #pragma unroll
            for (int w = 0; w < 4; ++w) s += red[((size_t)w*64 + lane)*21 + r*4 + k];
            corr_p[(size_t)cb*270400 + ((size_t)(m*8+pr)*65 + (y0 + half*5 + r))*65 + x] = s;
          }
        }
      }
    }
  } else {
    // ======== 5-row tile, rows 60..64 (r8-proven body) ========
    const int y0 = 60;
    const size_t rowbase = ((size_t)(m*4 + cb) * 96 + y0) * 96;
    for (int k = tid; k < 36*48; k += 256) {
      const int rho = k / 48, px = k - (k/48)*48;
      cp16(&satT[(rowbase + (size_t)rho*96 + x0 + px)*8], &patch[(size_t)k*8]);
    }
    asm volatile("s_waitcnt vmcnt(0)" ::: "memory");
    __syncthreads();

    floatx4 acc[5];
    #pragma unroll
    for (int r = 0; r < 5; ++r) acc[r] = (floatx4){0.f, 0.f, 0.f, 0.f};

    #pragma unroll
    for (int jbi = 0; jbi < 2; ++jbi) {
      const int jb = wave*2 + jbi;
      const int apx = pr + jb*4 + q;
      const u16* bp = gP + ((size_t)cb*1024 + (size_t)(jb*4+q))*128 + (size_t)pr*8;

      uint4 Br[8];
      #pragma unroll
      for (int ii = 0; ii < 8; ++ii) Br[ii] = *(const uint4*)(bp + (size_t)ii*4096);
      uint4 Ah[8];
      #pragma unroll
      for (int s = 0; s < 6; ++s) Ah[s] = *(const uint4*)(&patch[((size_t)s*48 + apx)*8]);

      #pragma unroll
      for (int i = 0; i < 32; ++i) {
        if (i < 30)
          Ah[(i+6)&7] = *(const uint4*)(&patch[((size_t)(i+6)*48 + apx)*8]);
        const bf16x8 bf = __builtin_bit_cast(bf16x8, Br[i&7]);
        if (i < 24)
          Br[(i+8)&7] = *(const uint4*)(bp + (size_t)(i+8)*4096);
        #pragma unroll
        for (int r = 0; r < 5; ++r)
          acc[r] = __builtin_amdgcn_mfma_f32_16x16x32_bf16(
              __builtin_bit_cast(bf16x8, Ah[(i+r)&7]), bf, acc[r], 0, 0, 0);
      }
    }

    float vals[20];
    #pragma unroll
    for (int r = 0; r < 5; ++r)
      #pragma unroll
      for (int k = 0; k < 4; ++k)
        vals[r*4+k] = acc[r][k] + __shfl_xor(acc[r][k], 8);

    __syncthreads();
    float* red = (float*)patch;
    #pragma unroll
    for (int u = 0; u < 20; ++u) red[((size_t)wave*64 + lane)*21 + u] = vals[u];
    __syncthreads();
    if (wave == 0 && pr < 8) {
      #pragma unroll
      for (int r = 0; r < 5; ++r) {
        #pragma unroll
        for (int k = 0; k < 4; ++k) {
          const int x = x0 + q*4 + k;
          float s = 0.f;
          #pragma unroll
          for (int w = 0; w < 4; ++w) s += red[((size_t)w*64 + lane)*21 + r*4 + k];
          corr_p[(size_t)cb*270400 + ((size_t)(m*8+pr)*65 + (y0+r))*65 + x] = s;
        }
      }
    }
  }
}

// ---- K3: fused normalize/max/refine (unchanged from r8). ----
__global__ __launch_bounds__(256) void k_post(
    const float* __restrict__ corr_p, const float* __restrict__ part,
    const float* __restrict__ nrmp, const float* __restrict__ gnrm,
    const int* __restrict__ tm, const float* __restrict__ grd,
    const float* __restrict__ sat, const float* __restrict__ gmask,
    u32* __restrict__ pmaxE, u32* __restrict__ grpcnt,
    u32* __restrict__ candcnt, u64* __restrict__ cand,
    float* __restrict__ out)
{
  __shared__ float red[256];
  __shared__ float s_bcast;
  __shared__ int s_last;
  __shared__ int fidx[128];
  __shared__ u32 fcnt;

  const int bi = blockIdx.x;
  const int m = bi / 40, n = (bi / 5) & 7, yc = bi % 5, g = m*8 + n;
  const int t = threadIdx.x;
  const bool diag = (m == n);

  red[t] = (t < 96) ? nrmp[m*96 + t] : 0.f;
  __syncthreads();
  for (int s = 128; s > 0; s >>= 1) { if (t < s) red[t] += red[t+s]; __syncthreads(); }
  const float srn = 1.f / fmaxf(sqrtf(red[0]), 1e-12f);
  const float grn = 1.f / fmaxf(sqrtf(gnrm[n]), 1e-12f);
  const float cscale = grn * srn, pscale = srn * srn;
  const int method = tm[0];

  const float* cp = corr_p + (size_t)g*4225;
  const float* pp = part + (size_t)m*4225;
  const int i0 = yc*845, i1 = i0 + 845;
  float vv[4];
  float bestv = -3.4e38f;
  #pragma unroll
  for (int k = 0; k < 4; ++k) {
    const int idx = i0 + k*256 + t;
    float v = -3.4e38f;
    if (idx < i1) {
      const float c = cp[idx] + cp[idx+270400] + cp[idx+540800] + cp[idx+811200];
      const float pt = pp[idx] * pscale;
      float denom = (method == 0) ? sqrtf(pt) : pt;
      denom = fmaxf(denom, 1e-12f);
      v = c * cscale / denom;
    }
    vv[k] = v;
    bestv = fmaxf(bestv, v);
  }
  __syncthreads();
  red[t] = bestv; __syncthreads();
  for (int s = 128; s > 0; s >>= 1) { if (t < s) red[t] = fmaxf(red[t], red[t+s]); __syncthreads(); }
  if (t == 0) { s_bcast = red[0]; atomicExch(&pmaxE[bi], encf(red[0])); }
  __syncthreads();
  if (diag) {
    const float lthr = s_bcast - 3e-3f;
    #pragma unroll
    for (int k = 0; k < 4; ++k) {
      const int idx = i0 + k*256 + t;
      if (idx < i1 && vv[k] >= lthr) {
        const u32 s = atomicAdd(&candcnt[n], 1u);
        if (s < 128)
          atomicExch(&cand[n*128 + s],
                     ((u64)__builtin_bit_cast(u32, vv[k]) << 32) | (u32)idx);
      }
    }
  }
  __syncthreads();
  if (t == 0) s_last = (atomicAdd(&grpcnt[g], 1u) == 4u) ? 1 : 0;
  __syncthreads();
  if (!s_last) return;

  if (t == 0) {
    float gm = -3.4e38f;
    #pragma unroll
    for (int k = 0; k < 5; ++k) gm = fmaxf(gm, decf(atomicOr(&pmaxE[g*5 + k], 0u)));
    out[g] = gm;
    s_bcast = gm;
  }
  __syncthreads();
  if (!diag) return;

  const float gmax = s_bcast;
  const float thr = gmax - 3e-3f;
  if (t == 0) fcnt = 0u;
  __syncthreads();
  u32 nc = atomicAdd(&candcnt[n], 0u); if (nc > 128) nc = 128;
  if (t < (int)nc) {
    const u64 pk = atomicAdd(&cand[n*128 + t], 0ULL);
    const float vf = __builtin_bit_cast(float, (u32)(pk >> 32));
    const int idx = (int)(u32)pk;
    if (vf >= thr) { const u32 s = atomicAdd(&fcnt, 1u); fidx[s] = idx; }
  }
  __syncthreads();
  if (t == 0 && fcnt == 0u) { fidx[0] = 0; fcnt = 1u; }
  __syncthreads();
  const int nf = (int)fcnt;

  __shared__ float sbest; __shared__ int sbix;
  if (t == 0) { sbest = -3.4e38f; sbix = 0x7FFFFFFF; }
  __syncthreads();
  const int c = t >> 3, s8 = t & 7;
  for (int ci = 0; ci < nf; ++ci) {
    const int idx = fidx[ci];
    const int y = idx / 65, x = idx - y*65;
    float a = 0.f;
    #pragma unroll
    for (int ii = 0; ii < 4; ++ii) {
      const int i = s8 + ii*8;
      const float* gr = grd + ((size_t)n*32 + c)*1024 + i*32;
      const float* sr = sat + (((size_t)n*32 + c)*128 + (16 + y + i))*128 + (16 + x);
      #pragma unroll
      for (int j = 0; j < 32; ++j) a += gr[j] * sr[j];
    }
    red[t] = a; __syncthreads();
    for (int st = 128; st > 0; st >>= 1) { if (t < st) red[t] += red[t+st]; __syncthreads(); }
    if (t == 0) {
      const float pt = part[(size_t)n*4225 + idx] * pscale;
      float denom = (method == 0) ? sqrtf(pt) : pt;
      denom = fmaxf(denom, 1e-12f);
      const float v = red[0] * cscale / denom;
      if (v > sbest || (v == sbest && idx < sbix)) { sbest = v; sbix = idx; }
    }
    __syncthreads();
  }
  const int bix = sbix;
  const int ph = bix / 65, pw = bix - (bix/65)*65;
  for (int p = t; p < 9216; p += 256) {
    const int yy = p / 96, xx = p - yy*96;
    float val = 0.f;
    if (yy >= ph && yy < ph+32 && xx >= pw && xx < pw+32)
      val = gmask[n*1024 + (yy-ph)*32 + (xx-pw)];
    out[64 + (size_t)n*9216 + p] = val;
  }
}

extern "C" void kernel_launch(void* const* d_in, const int* in_sizes, int n_in,
                              void* d_out, int out_size, void* d_ws, size_t ws_size,
                              hipStream_t stream) {
  const float* grd = (const float*)d_in[0];
  const float* sat = (const float*)d_in[1];
  const int*   tm  = (const int*)d_in[2];
  float* out = (float*)d_out;
  char* ws = (char*)d_ws;

  float* corrp = (float*)(ws + OFF_CORRP);
  u16*   sTh   = (u16*)(ws + OFF_SATT);
  u16*   gP    = (u16*)(ws + OFF_GRDP);
  float* s2    = (float*)(ws + OFF_S2);
  float* part  = (float*)(ws + OFF_PART);
  float* nrmp  = (float*)(ws + OFF_NRMP);
  float* gnrm  = (float*)(ws + OFF_GNRM);
  float* gmask = (float*)(ws + OFF_MASK);
  u32*   pmaxE = (u32*)(ws + OFF_PMAX);
  u32*   cnts  = (u32*)(ws + OFF_CNT);
  u64*   cand  = (u64*)(ws + OFF_CAND);

  k_prep<<<777,  256, 0, stream>>>(grd, sat, sTh, gP, s2, nrmp, gnrm, gmask, cnts);
  k_conv<<<1128, 256, 0, stream>>>(sTh, gP, s2, corrp, part);
  k_post<<<320,  256, 0, stream>>>(corrp, part, nrmp, gnrm, tm, grd, sat, gmask,
                                   pmaxE, cnts, cnts + 64, cand, out);
}